// Round 12
// baseline (360.276 us; speedup 1.0000x reference)
//
#include <hip/hip_runtime.h>
#include <hip/hip_bf16.h>
#include <stdint.h>

#define NH 16
#define NKV 8
#define HD 128
#define BB 4
#define SS 1024
#define CTXL 2048
#define LT 3072
#define HID 2048
#define QKVN 4096
#define MROWS 4096

typedef __hip_bfloat16 bf16;
using f32x4 = __attribute__((ext_vector_type(4))) float;
using s16x8 = __attribute__((ext_vector_type(8))) short;

#define MFMA(a, b, c) __builtin_amdgcn_mfma_f32_16x16x32_bf16((a), (b), (c), 0, 0, 0)

__device__ __forceinline__ void gload_lds16(const void* g, void* l) {
  __builtin_amdgcn_global_load_lds((const __attribute__((address_space(1))) void*)g,
                                   (__attribute__((address_space(3))) void*)l, 16, 0, 0);
}

__device__ __forceinline__ void store_bf8(bf16* dst, const float* f) {
  bf16 tmp[8];
#pragma unroll
  for (int j = 0; j < 8; ++j) tmp[j] = __float2bfloat16(f[j]);
  __builtin_memcpy((void*)dst, (const void*)tmp, 16);
}

// ---------------- prep kernels ----------------

__global__ void cvt_bf16(const float* __restrict__ in, bf16* __restrict__ out) {
  size_t tid = (size_t)blockIdx.x * 256 + threadIdx.x;  // one thread per 8 elems
  const float4* p = (const float4*)(in + tid * 8);
  float4 a = p[0], b = p[1];
  float f[8] = {a.x, a.y, a.z, a.w, b.x, b.y, b.z, b.w};
  store_bf8(out + tid * 8, f);
}

// out[c][r] = (bf16) in[r][c]
__global__ void transpose_cvt(const float* __restrict__ in, bf16* __restrict__ out,
                              int R, int C) {
  __shared__ float tile[32][33];
  int c0 = blockIdx.x * 32, r0 = blockIdx.y * 32;
  int tx = threadIdx.x & 31, ty = threadIdx.x >> 5;
#pragma unroll
  for (int i = 0; i < 32; i += 8)
    tile[ty + i][tx] = in[(size_t)(r0 + ty + i) * C + c0 + tx];
  __syncthreads();
#pragma unroll
  for (int i = 0; i < 32; i += 8)
    out[(size_t)(c0 + ty + i) * R + r0 + tx] = __float2bfloat16(tile[tx][ty + i]);
}

// ctx_k [b][l][h][d] f32 -> K_full [b][h][l][d] bf16 (l < CTXL)
__global__ void ctxk_copy(const float* __restrict__ ck, bf16* __restrict__ Kf) {
  int tid = blockIdx.x * 256 + threadIdx.x;
  int d8 = tid & 15, l = (tid >> 4) & 2047, h = (tid >> 15) & 7, b = tid >> 18;
  const float* s = ck + (((size_t)b * CTXL + l) * NKV + h) * HD + d8 * 8;
  const float4* p = (const float4*)s;
  float4 a = p[0], bb = p[1];
  float f[8] = {a.x, a.y, a.z, a.w, bb.x, bb.y, bb.z, bb.w};
  store_bf8(Kf + (((size_t)(b * NKV + h)) * LT + l) * HD + d8 * 8, f);
}

// ctx_v [b][l][h][d] f32 -> V_T [b][h][d][l] bf16 (l < CTXL)
__global__ void ctxv_transpose(const float* __restrict__ cv, bf16* __restrict__ Vt) {
  __shared__ float tile[32][33];
  int l0 = blockIdx.x * 32, d0 = blockIdx.y * 32;
  int b = blockIdx.z >> 3, h = blockIdx.z & 7;
  int tx = threadIdx.x & 31, ty = threadIdx.x >> 5;
#pragma unroll
  for (int i = 0; i < 32; i += 8)
    tile[ty + i][tx] = cv[(((size_t)b * CTXL + l0 + ty + i) * NKV + h) * HD + d0 + tx];
  __syncthreads();
#pragma unroll
  for (int i = 0; i < 32; i += 8)
    Vt[(((size_t)(b * NKV + h)) * HD + d0 + ty + i) * LT + l0 + tx] =
        __float2bfloat16(tile[tx][ty + i]);
}

// qkv v-slice -> V_T tail (l = CTXL + s)
__global__ void vt_from_qkv(const bf16* __restrict__ qkv, bf16* __restrict__ Vt) {
  __shared__ float tile[32][33];
  int s0 = blockIdx.x * 32, d0 = blockIdx.y * 32;
  int b = blockIdx.z >> 3, h = blockIdx.z & 7;
  int tx = threadIdx.x & 31, ty = threadIdx.x >> 5;
#pragma unroll
  for (int i = 0; i < 32; i += 8)
    tile[ty + i][tx] = __bfloat162float(
        qkv[((size_t)b * SS + s0 + ty + i) * QKVN + 3072 + h * HD + d0 + tx]);
  __syncthreads();
#pragma unroll
  for (int i = 0; i < 32; i += 8)
    Vt[(((size_t)(b * NKV + h)) * HD + d0 + ty + i) * LT + CTXL + s0 + tx] =
        __float2bfloat16(tile[tx][ty + i]);
}

__global__ void rope_table(const int* __restrict__ pid, float* __restrict__ cosT,
                           float* __restrict__ sinT) {
  int tid = blockIdx.x * 256 + threadIdx.x;  // S*64
  int j = tid & 63, s = tid >> 6;
  int sec = (j < 8) ? 0 : (j < 16) ? 1 : (j < 40) ? 2 : 3;
  float pos = (float)pid[sec * SS + s];
  float inv = __expf(-(float)j * 0.14391156831212787f);  // ln(10000)/64
  float a = pos * inv;
  cosT[tid] = cosf(a);
  sinT[tid] = sinf(a);
}

__global__ void rope_q(const bf16* __restrict__ qkv, const float* __restrict__ cosT,
                       const float* __restrict__ sinT, bf16* __restrict__ Q) {
  int tid = blockIdx.x * 256 + threadIdx.x;
  int j = tid & 63, h = (tid >> 6) & 15, s = (tid >> 10) & 1023, b = tid >> 20;
  const bf16* src = qkv + ((size_t)b * SS + s) * QKVN + h * HD;
  float x1 = __bfloat162float(src[j]), x2 = __bfloat162float(src[j + 64]);
  float c = cosT[s * 64 + j], sn = sinT[s * 64 + j];
  bf16* dst = Q + (((size_t)(b * NH + h)) * SS + s) * HD;
  dst[j] = __float2bfloat16(x1 * c - x2 * sn);
  dst[j + 64] = __float2bfloat16(x2 * c + x1 * sn);
}

__global__ void rope_k(const bf16* __restrict__ qkv, const float* __restrict__ cosT,
                       const float* __restrict__ sinT, bf16* __restrict__ Kf) {
  int tid = blockIdx.x * 256 + threadIdx.x;
  int j = tid & 63, h = (tid >> 6) & 7, s = (tid >> 9) & 1023, b = tid >> 19;
  const bf16* src = qkv + ((size_t)b * SS + s) * QKVN + 2048 + h * HD;
  float x1 = __bfloat162float(src[j]), x2 = __bfloat162float(src[j + 64]);
  float c = cosT[s * 64 + j], sn = sinT[s * 64 + j];
  bf16* dst = Kf + (((size_t)(b * NKV + h)) * LT + CTXL + s) * HD;
  dst[j] = __float2bfloat16(x1 * c - x2 * sn);
  dst[j + 64] = __float2bfloat16(x2 * c + x1 * sn);
}

// ---------------- GEMM: C[M][N] = A[M][K] * BT[N][K]^T ----------------
// 256x128 tile, BK=64, 8 waves (4M x 2N), 512 threads. 3-buffer LDS (144 KB),
// prefetch depth 2, ONE barrier per K-tile, counted s_waitcnt vmcnt(6).
// XOR chunk swizzle both sides (rule 21). T1 XCD swizzle + T5 setprio kept.

template <typename OT>
__global__ __launch_bounds__(512, 1) void gemm_bt(const bf16* __restrict__ A,
                                                  const bf16* __restrict__ BT,
                                                  OT* __restrict__ C, int M, int N,
                                                  int K) {
  __shared__ __attribute__((aligned(16))) bf16 lA[3][256][64];  // 96 KB
  __shared__ __attribute__((aligned(16))) bf16 lB[3][128][64];  // 48 KB
  const int t = threadIdx.x;
  const int lane = t & 63, w = t >> 6;
  const int wr = w >> 1, wc = w & 1;
  const int lrow = lane & 15, kgrp = lane >> 4;
  const int rchk = lrow & 7;  // read-side swizzle bits (frag row & 7)
  // T1: XCD-aware bijective remap (nwg % 8 == 0)
  const int lin = blockIdx.y * gridDim.x + blockIdx.x;
  const int qq = (gridDim.x * gridDim.y) >> 3;
  const int swz = (lin & 7) * qq + (lin >> 3);
  const int bx = swz % gridDim.x, by = swz / gridDim.x;
  const int m0 = by * 256, n0 = bx * 128;
  const int srow = lane >> 3;              // 0..7: row within 8-row group
  const int schk = (lane & 7) ^ srow;      // pre-swizzled source chunk
  const f32x4 fz = {0.f, 0.f, 0.f, 0.f};
  f32x4 acc[4][4];
#pragma unroll
  for (int i = 0; i < 4; ++i)
#pragma unroll
    for (int j = 0; j < 4; ++j) acc[i][j] = fz;
  const int NTK = K >> 6;

#define GSTAGE(ib, kt)                                                      \
  do {                                                                      \
    _Pragma("unroll") for (int c = 0; c < 4; ++c) {                         \
      int ra = c * 64 + w * 8 + srow;                                       \
      gload_lds16(A + (size_t)(m0 + ra) * K + (kt)*64 + schk * 8,           \
                  &lA[ib][c * 64 + w * 8][0]);                              \
    }                                                                       \
    _Pragma("unroll") for (int c = 0; c < 2; ++c) {                         \
      int rb = c * 64 + w * 8 + srow;                                       \
      gload_lds16(BT + (size_t)(n0 + rb) * K + (kt)*64 + schk * 8,          \
                  &lB[ib][c * 64 + w * 8][0]);                              \
    }                                                                       \
  } while (0)

  GSTAGE(0, 0);
  GSTAGE(1, 1);
  int ib = 0;
  for (int kt = 0; kt < NTK; ++kt) {
    if (kt + 1 < NTK)
      asm volatile("s_waitcnt vmcnt(6) lgkmcnt(0)" ::: "memory");
    else
      asm volatile("s_waitcnt vmcnt(0) lgkmcnt(0)" ::: "memory");
    __builtin_amdgcn_s_barrier();
    __builtin_amdgcn_sched_barrier(0);
    if (kt + 2 < NTK) {
      int ib2 = ib + 2;
      if (ib2 >= 3) ib2 -= 3;
      GSTAGE(ib2, kt + 2);
    }
#pragma unroll
    for (int kk = 0; kk < 2; ++kk) {
      s16x8 af[4], bf[4];
#pragma unroll
      for (int i = 0; i < 4; ++i)
        af[i] = *(const s16x8*)&lA[ib][wr * 64 + i * 16 + lrow]
                                     [(((kk << 2) + kgrp) ^ rchk) * 8];
#pragma unroll
      for (int j = 0; j < 4; ++j)
        bf[j] = *(const s16x8*)&lB[ib][wc * 64 + j * 16 + lrow]
                                     [(((kk << 2) + kgrp) ^ rchk) * 8];
      __builtin_amdgcn_s_setprio(1);
#pragma unroll
      for (int i = 0; i < 4; ++i)
#pragma unroll
        for (int j = 0; j < 4; ++j) acc[i][j] = MFMA(af[i], bf[j], acc[i][j]);
      __builtin_amdgcn_s_setprio(0);
    }
    ++ib;
    if (ib >= 3) ib = 0;
  }
#undef GSTAGE

#pragma unroll
  for (int i = 0; i < 4; ++i)
#pragma unroll
    for (int j = 0; j < 4; ++j)
#pragma unroll
      for (int r = 0; r < 4; ++r) {
        int row = m0 + wr * 64 + i * 16 + kgrp * 4 + r;
        int col = n0 + wc * 64 + j * 16 + lrow;
        float v = acc[i][j][r];
        if constexpr (sizeof(OT) == 2)
          C[(size_t)row * N + col] = __float2bfloat16(v);
        else
          C[(size_t)row * N + col] = v;
      }
}

// ---------------- flash attention ----------------
// TLP experiment (R10 botched it: grid stayed 1 block/CU). 128 q-rows/block,
// 4 waves x 32 rows (per-wave structure IDENTICAL to the 152us R6 kernel),
// grid 512 -> 2 independent blocks/CU (same 8 waves/CU, two barrier groups
// that can anti-phase). K double-buffered; V single-buffered (staged at top,
// consumed after barrier #1 -> DMA hides under QK+softmax). LDS 66 KB.
// Swapped QK^T, lane-local softmax, deferred l, defer-max (T13).
// XOR chunk swizzle both sides (rule 21): K chunk^(row&15), V chunk^(d&7).

#define PSTR 72  // P row stride in elements: 144B = 16B-aligned
#define NT 48    // LT / 64
#define SCALE2 0.1275174335919605f  // scale * log2(e)

__global__ __launch_bounds__(256, 2) void flash_attn(
    const bf16* __restrict__ Q, const bf16* __restrict__ Kf,
    const bf16* __restrict__ Vt, bf16* __restrict__ O) {
  __shared__ __attribute__((aligned(16))) bf16 Kl[2][64][128];      // 32 KB
  __shared__ __attribute__((aligned(16))) bf16 Vl[128][64];         // 16 KB
  __shared__ __attribute__((aligned(16))) bf16 P_lds[4][32][PSTR];  // 18 KB
  const int t = threadIdx.x, lane = t & 63, w = t >> 6;  // w: 0..3
  const int qb = blockIdx.x & 7, h = (blockIdx.x >> 3) & 15, b = blockIdx.x >> 7;
  const int hk = h >> 1;
  const int lrow = lane & 15, kgrp = lane >> 4;
  const bf16* Kp = Kf + (size_t)(b * NKV + hk) * LT * HD;
  const bf16* Vp = Vt + (size_t)(b * NKV + hk) * HD * LT;

  const bf16* Qp = Q + (((size_t)(b * NH + h)) * SS + qb * 128 + w * 32) * HD;
  s16x8 qf[2][4];
#pragma unroll
  for (int f = 0; f < 2; ++f)
#pragma unroll
    for (int kd = 0; kd < 4; ++kd)
      qf[f][kd] = *(const s16x8*)&Qp[(f * 16 + lrow) * HD + kd * 32 + kgrp * 8];

  const f32x4 fz = {0.f, 0.f, 0.f, 0.f};
  f32x4 acc[2][8];
#pragma unroll
  for (int f = 0; f < 2; ++f)
#pragma unroll
    for (int i = 0; i < 8; ++i) acc[f][i] = fz;
  // per-lane: m_/l_ track q-row (lane&15) of each frag; l_ is the partial
  // sum over this lane's kv subset (cross-kgrp reduce deferred to epilogue)
  float m_[2] = {-1e30f, -1e30f}, l_[2] = {0.f, 0.f};

  // staging geometry (4 waves, 256 threads, 4 loads/thread each)
#define STAGE_K(buf, l0)                                                        \
  do {                                                                          \
    _Pragma("unroll") for (int c = 0; c < 4; ++c) {                             \
      int row = w * 16 + c * 4 + (lane >> 4);                                   \
      gload_lds16(Kp + (size_t)((l0) + row) * HD + ((lane & 15) ^ (row & 15)) * 8, \
                  &Kl[buf][w * 16 + c * 4][0]);                                 \
    }                                                                           \
  } while (0)
#define STAGE_V(l0)                                                             \
  do {                                                                          \
    _Pragma("unroll") for (int c = 0; c < 4; ++c) {                             \
      int d = w * 32 + c * 8 + (lane >> 3);                                     \
      gload_lds16(Vp + (size_t)d * LT + (l0) + ((lane & 7) ^ (d & 7)) * 8,      \
                  &Vl[w * 32 + c * 8][0]);                                      \
    }                                                                           \
  } while (0)

  STAGE_K(0, 0);
  __syncthreads();

  for (int tt = 0; tt < NT; ++tt) {
    const int cur = tt & 1;
    STAGE_V(tt * 64);
    if (tt + 1 < NT) STAGE_K(cur ^ 1, (tt + 1) * 64);

    // QK^T swapped: sc[f][cf][r] = score for q-row (lane&15) of frag f,
    // kv = cf*16 + kgrp*4 + r
    f32x4 sc[2][4];
#pragma unroll
    for (int f = 0; f < 2; ++f)
#pragma unroll
      for (int cf = 0; cf < 4; ++cf) sc[f][cf] = fz;
#pragma unroll
    for (int cf = 0; cf < 4; ++cf)
#pragma unroll
      for (int kd = 0; kd < 4; ++kd) {
        s16x8 kb =
            *(const s16x8*)&Kl[cur][cf * 16 + lrow][((kd * 4 + kgrp) ^ lrow) * 8];
#pragma unroll
        for (int f = 0; f < 2; ++f) sc[f][cf] = MFMA(kb, qf[f][kd], sc[f][cf]);
      }

    // lane-local max over this lane's 16 scores, then 2 wide shfls
    float mxv[2];
#pragma unroll
    for (int f = 0; f < 2; ++f) {
      float a0 = fmaxf(fmaxf(sc[f][0][0], sc[f][0][1]),
                       fmaxf(sc[f][0][2], sc[f][0][3]));
      float a1 = fmaxf(fmaxf(sc[f][1][0], sc[f][1][1]),
                       fmaxf(sc[f][1][2], sc[f][1][3]));
      float a2 = fmaxf(fmaxf(sc[f][2][0], sc[f][2][1]),
                       fmaxf(sc[f][2][2], sc[f][2][3]));
      float a3 = fmaxf(fmaxf(sc[f][3][0], sc[f][3][1]),
                       fmaxf(sc[f][3][2], sc[f][3][3]));
      float mx = fmaxf(fmaxf(a0, a1), fmaxf(a2, a3)) * SCALE2;
      mx = fmaxf(mx, __shfl_xor(mx, 16, 64));
      mx = fmaxf(mx, __shfl_xor(mx, 32, 64));
      mxv[f] = mx;
    }
    bool nb = (mxv[0] > m_[0] + 8.f) || (mxv[1] > m_[1] + 8.f);
    if (__any(nb)) {
#pragma unroll
      for (int f = 0; f < 2; ++f) {
        float mn = fmaxf(m_[f], mxv[f]);
        float so = exp2f(m_[f] - mn);
        m_[f] = mn;
        l_[f] *= so;
        float sob[4];
#pragma unroll
        for (int r = 0; r < 4; ++r) sob[r] = __shfl(so, kgrp * 4 + r, 16);
#pragma unroll
        for (int nd = 0; nd < 8; ++nd)
#pragma unroll
          for (int r = 0; r < 4; ++r) acc[f][nd][r] *= sob[r];
      }
    }
    // P: exp2, accumulate lane-partial l, pack 4 bf16 -> one b64 store per cf
#pragma unroll
    for (int f = 0; f < 2; ++f) {
      float lp = 0.f;
#pragma unroll
      for (int cf = 0; cf < 4; ++cf) {
        bf16 pk[4];
#pragma unroll
        for (int r = 0; r < 4; ++r) {
          float p = exp2f(sc[f][cf][r] * SCALE2 - m_[f]);
          lp += p;
          pk[r] = __float2bfloat16(p);
        }
        __builtin_memcpy((void*)&P_lds[w][f * 16 + lrow][cf * 16 + kgrp * 4], pk, 8);
      }
      l_[f] += lp;
    }

    // per-wave LDS: in-wave write->read ordering via lgkmcnt, no barrier
    s16x8 pa[2][2];
#pragma unroll
    for (int f = 0; f < 2; ++f)
#pragma unroll
      for (int kc = 0; kc < 2; ++kc)
        pa[f][kc] = *(const s16x8*)&P_lds[w][f * 16 + lrow][kc * 32 + kgrp * 8];

    __syncthreads();  // barrier #1: drains V(tt) + K(tt+1) DMA (vmcnt 0)

    // PV: each vb fragment feeds both row-frags
#pragma unroll
    for (int nd = 0; nd < 8; ++nd)
#pragma unroll
      for (int kc = 0; kc < 2; ++kc) {
        s16x8 vb = *(const s16x8*)&Vl[nd * 16 + lrow]
                                     [((kc * 4 + kgrp) ^ (lrow & 7)) * 8];
#pragma unroll
        for (int f = 0; f < 2; ++f) acc[f][nd] = MFMA(pa[f][kc], vb, acc[f][nd]);
      }
    __syncthreads();  // barrier #2: protect Vl / Kl[cur] before next STAGE
  }
#undef STAGE_K
#undef STAGE_V

  // epilogue: reduce l across kgrp (2 shfls), broadcast per acc-row, store
  float li[2][4];
#pragma unroll
  for (int f = 0; f < 2; ++f) {
    float lv = l_[f];
    lv += __shfl_xor(lv, 16, 64);
    lv += __shfl_xor(lv, 32, 64);
#pragma unroll
    for (int r = 0; r < 4; ++r) li[f][r] = 1.f / __shfl(lv, kgrp * 4 + r, 16);
  }
#pragma unroll
  for (int f = 0; f < 2; ++f)
#pragma unroll
    for (int nd = 0; nd < 8; ++nd)
#pragma unroll
      for (int r = 0; r < 4; ++r) {
        int row = qb * 128 + w * 32 + f * 16 + kgrp * 4 + r;
        O[((size_t)b * SS + row) * 2048 + h * HD + nd * 16 + lrow] =
            __float2bfloat16(acc[f][nd][r] * li[f][r]);
      }
}

// ---------------- launch ----------------

extern "C" void kernel_launch(void* const* d_in, const int* in_sizes, int n_in,
                              void* d_out, int out_size, void* d_ws, size_t ws_size,
                              hipStream_t stream) {
  const float* hs = (const float*)d_in[0];
  const float* Wqkv = (const float*)d_in[1];
  const float* Wo = (const float*)d_in[2];
  const float* ctx_k = (const float*)d_in[3];
  const float* ctx_v = (const float*)d_in[4];
  const int* pid = (const int*)d_in[5];
  float* out = (float*)d_out;
  char* ws = (char*)d_ws;

  bf16* Hb = (bf16*)(ws);                      // 16.78 MB (reused as attn_out)
  bf16* WqT = (bf16*)(ws + 16777216);          // 16.78 MB
  bf16* WoT = (bf16*)(ws + 33554432);          // 8.39 MB
  bf16* qkv = (bf16*)(ws + 41943040);          // 33.55 MB
  bf16* Qb = (bf16*)(ws + 75497472);           // 16.78 MB
  bf16* Kfull = (bf16*)(ws + 92274688);        // 25.17 MB
  bf16* Vt = (bf16*)(ws + 117440512);          // 25.17 MB
  float* cosT = (float*)(ws + 142606336);      // 256 KB
  float* sinT = (float*)(ws + 142606336 + 262144);
  bf16* attn = Hb;  // alias: Hb dead after QKV GEMM

  rope_table<<<256, 256, 0, stream>>>(pid, cosT, sinT);
  cvt_bf16<<<4096, 256, 0, stream>>>(hs, Hb);
  transpose_cvt<<<dim3(128, 64), 256, 0, stream>>>(Wqkv, WqT, HID, QKVN);
  transpose_cvt<<<dim3(64, 64), 256, 0, stream>>>(Wo, WoT, 2048, 2048);
  ctxk_copy<<<4096, 256, 0, stream>>>(ctx_k, Kfull);
  ctxv_transpose<<<dim3(64, 4, 32), 256, 0, stream>>>(ctx_v, Vt);
  gemm_bt<bf16><<<dim3(QKVN / 128, MROWS / 256), 512, 0, stream>>>(
      Hb, WqT, qkv, MROWS, QKVN, HID);
  rope_q<<<16384, 256, 0, stream>>>(qkv, cosT, sinT, Qb);
  rope_k<<<8192, 256, 0, stream>>>(qkv, cosT, sinT, Kfull);
  vt_from_qkv<<<dim3(32, 4, 32), 256, 0, stream>>>(qkv, Vt);
  flash_attn<<<512, 256, 0, stream>>>(Qb, Kfull, Vt, attn);
  gemm_bt<float><<<dim3(2048 / 128, MROWS / 256), 512, 0, stream>>>(
      attn, WoT, out, MROWS, 2048, HID);
}

// Round 13
// 340.038 us; speedup vs baseline: 1.0595x; 1.0595x over previous
//
#include <hip/hip_runtime.h>
#include <hip/hip_bf16.h>
#include <stdint.h>

#define NH 16
#define NKV 8
#define HD 128
#define BB 4
#define SS 1024
#define CTXL 2048
#define LT 3072
#define HID 2048
#define QKVN 4096
#define MROWS 4096

typedef __hip_bfloat16 bf16;
using f32x4 = __attribute__((ext_vector_type(4))) float;
using s16x8 = __attribute__((ext_vector_type(8))) short;

#define MFMA(a, b, c) __builtin_amdgcn_mfma_f32_16x16x32_bf16((a), (b), (c), 0, 0, 0)

__device__ __forceinline__ void gload_lds16(const void* g, void* l) {
  __builtin_amdgcn_global_load_lds((const __attribute__((address_space(1))) void*)g,
                                   (__attribute__((address_space(3))) void*)l, 16, 0, 0);
}

__device__ __forceinline__ void store_bf8(bf16* dst, const float* f) {
  bf16 tmp[8];
#pragma unroll
  for (int j = 0; j < 8; ++j) tmp[j] = __float2bfloat16(f[j]);
  __builtin_memcpy((void*)dst, (const void*)tmp, 16);
}

__device__ __forceinline__ float bf2f(short x) {
  unsigned int u = ((unsigned int)(unsigned short)x) << 16;
  float f;
  __builtin_memcpy(&f, &u, 4);
  return f;
}

// ---------------- prep1: cvt + weight transposes + rope table + ctx K/V ----
// block ranges (256 thr each):
//   [0,4096)            cvt_bf16 (hs -> Hb)
//   [4096,12288)        transpose Wqkv (2048x4096 -> WqT 4096x2048)
//   [12288,16384)       transpose Wo (2048x2048 -> WoT)
//   [16384,16640)       rope_table
//   [16640,20736)       ctx_k copy -> Kfull
//   [20736,28928)       ctx_v transpose -> Vt
#define P1_CVT 4096
#define P1_WQ (P1_CVT + 8192)
#define P1_WO (P1_WQ + 4096)
#define P1_RT (P1_WO + 256)
#define P1_CK (P1_RT + 4096)
#define P1_CV (P1_CK + 8192)

__global__ void prep1(const float* __restrict__ hs, const float* __restrict__ Wqkv,
                      const float* __restrict__ Wo, const float* __restrict__ ck,
                      const float* __restrict__ cv, const int* __restrict__ pid,
                      bf16* __restrict__ Hb, bf16* __restrict__ WqT,
                      bf16* __restrict__ WoT, bf16* __restrict__ Kf,
                      bf16* __restrict__ Vt, float* __restrict__ cosT,
                      float* __restrict__ sinT) {
  __shared__ float tile[32][33];
  const int blk = blockIdx.x, thr = threadIdx.x;
  if (blk < P1_CVT) {
    size_t tid = (size_t)blk * 256 + thr;
    const float4* p = (const float4*)(hs + tid * 8);
    float4 a = p[0], b = p[1];
    float f[8] = {a.x, a.y, a.z, a.w, b.x, b.y, b.z, b.w};
    store_bf8(Hb + tid * 8, f);
  } else if (blk < P1_WQ) {
    int j = blk - P1_CVT;
    int c0 = (j & 127) * 32, r0 = (j >> 7) * 32;  // R=2048 C=4096
    int tx = thr & 31, ty = thr >> 5;
#pragma unroll
    for (int i = 0; i < 32; i += 8)
      tile[ty + i][tx] = Wqkv[(size_t)(r0 + ty + i) * QKVN + c0 + tx];
    __syncthreads();
#pragma unroll
    for (int i = 0; i < 32; i += 8)
      WqT[(size_t)(c0 + ty + i) * HID + r0 + tx] = __float2bfloat16(tile[tx][ty + i]);
  } else if (blk < P1_WO) {
    int j = blk - P1_WQ;
    int c0 = (j & 63) * 32, r0 = (j >> 6) * 32;  // 2048x2048
    int tx = thr & 31, ty = thr >> 5;
#pragma unroll
    for (int i = 0; i < 32; i += 8)
      tile[ty + i][tx] = Wo[(size_t)(r0 + ty + i) * 2048 + c0 + tx];
    __syncthreads();
#pragma unroll
    for (int i = 0; i < 32; i += 8)
      WoT[(size_t)(c0 + ty + i) * 2048 + r0 + tx] = __float2bfloat16(tile[tx][ty + i]);
  } else if (blk < P1_RT) {
    int tid = (blk - P1_WO) * 256 + thr;  // S*64
    int j = tid & 63, s = tid >> 6;
    int sec = (j < 8) ? 0 : (j < 16) ? 1 : (j < 40) ? 2 : 3;
    float pos = (float)pid[sec * SS + s];
    float inv = __expf(-(float)j * 0.14391156831212787f);  // ln(10000)/64
    float a = pos * inv;
    cosT[tid] = cosf(a);
    sinT[tid] = sinf(a);
  } else if (blk < P1_CK) {
    int tid = (blk - P1_RT) * 256 + thr;
    int d8 = tid & 15, l = (tid >> 4) & 2047, h = (tid >> 15) & 7, b = tid >> 18;
    const float* s = ck + (((size_t)b * CTXL + l) * NKV + h) * HD + d8 * 8;
    const float4* p = (const float4*)s;
    float4 a = p[0], bb = p[1];
    float f[8] = {a.x, a.y, a.z, a.w, bb.x, bb.y, bb.z, bb.w};
    store_bf8(Kf + (((size_t)(b * NKV + h)) * LT + l) * HD + d8 * 8, f);
  } else {
    int j = blk - P1_CK;
    int l0 = (j & 63) * 32, d0 = ((j >> 6) & 3) * 32;
    int bz = j >> 8, b = bz >> 3, h = bz & 7;
    int tx = thr & 31, ty = thr >> 5;
#pragma unroll
    for (int i = 0; i < 32; i += 8)
      tile[ty + i][tx] =
          cv[(((size_t)b * CTXL + l0 + ty + i) * NKV + h) * HD + d0 + tx];
    __syncthreads();
#pragma unroll
    for (int i = 0; i < 32; i += 8)
      Vt[(((size_t)(b * NKV + h)) * HD + d0 + ty + i) * LT + l0 + tx] =
          __float2bfloat16(tile[tx][ty + i]);
  }
}

// ---------------- prep2: rope_k + vt_from_qkv (both read qkv) --------------
// [0,8192) rope_k ; [8192,12288) vt_from_qkv
__global__ void prep2(const bf16* __restrict__ qkv, const float* __restrict__ cosT,
                      const float* __restrict__ sinT, bf16* __restrict__ Kf,
                      bf16* __restrict__ Vt) {
  __shared__ float tile[32][33];
  const int blk = blockIdx.x, thr = threadIdx.x;
  if (blk < 8192) {
    int tid = blk * 256 + thr;
    int j = tid & 63, h = (tid >> 6) & 7, s = (tid >> 9) & 1023, b = tid >> 19;
    const bf16* src = qkv + ((size_t)b * SS + s) * QKVN + 2048 + h * HD;
    float x1 = __bfloat162float(src[j]), x2 = __bfloat162float(src[j + 64]);
    float c = cosT[s * 64 + j], sn = sinT[s * 64 + j];
    bf16* dst = Kf + (((size_t)(b * NKV + h)) * LT + CTXL + s) * HD;
    dst[j] = __float2bfloat16(x1 * c - x2 * sn);
    dst[j + 64] = __float2bfloat16(x2 * c + x1 * sn);
  } else {
    int j = blk - 8192;
    int s0 = (j & 31) * 32, d0 = ((j >> 5) & 3) * 32;
    int bz = j >> 7, b = bz >> 3, h = bz & 7;
    int tx = thr & 31, ty = thr >> 5;
#pragma unroll
    for (int i = 0; i < 32; i += 8)
      tile[ty + i][tx] = __bfloat162float(
          qkv[((size_t)b * SS + s0 + ty + i) * QKVN + 3072 + h * HD + d0 + tx]);
    __syncthreads();
#pragma unroll
    for (int i = 0; i < 32; i += 8)
      Vt[(((size_t)(b * NKV + h)) * HD + d0 + ty + i) * LT + CTXL + s0 + tx] =
          __float2bfloat16(tile[tx][ty + i]);
  }
}

// ---------------- GEMM: C[M][N] = A[M][K] * BT[N][K]^T ----------------
// 256x128 tile, BK=64, 8 waves (4M x 2N), 512 threads. 3-buffer LDS (144 KB),
// prefetch depth 2, ONE barrier per K-tile, counted s_waitcnt vmcnt(6).
// XOR chunk swizzle both sides (rule 21). T1 XCD swizzle + T5 setprio kept.

template <typename OT>
__global__ __launch_bounds__(512, 1) void gemm_bt(const bf16* __restrict__ A,
                                                  const bf16* __restrict__ BT,
                                                  OT* __restrict__ C, int M, int N,
                                                  int K) {
  __shared__ __attribute__((aligned(16))) bf16 lA[3][256][64];  // 96 KB
  __shared__ __attribute__((aligned(16))) bf16 lB[3][128][64];  // 48 KB
  const int t = threadIdx.x;
  const int lane = t & 63, w = t >> 6;
  const int wr = w >> 1, wc = w & 1;
  const int lrow = lane & 15, kgrp = lane >> 4;
  const int rchk = lrow & 7;  // read-side swizzle bits (frag row & 7)
  // T1: XCD-aware bijective remap (nwg % 8 == 0)
  const int lin = blockIdx.y * gridDim.x + blockIdx.x;
  const int qq = (gridDim.x * gridDim.y) >> 3;
  const int swz = (lin & 7) * qq + (lin >> 3);
  const int bx = swz % gridDim.x, by = swz / gridDim.x;
  const int m0 = by * 256, n0 = bx * 128;
  const int srow = lane >> 3;              // 0..7: row within 8-row group
  const int schk = (lane & 7) ^ srow;      // pre-swizzled source chunk
  const f32x4 fz = {0.f, 0.f, 0.f, 0.f};
  f32x4 acc[4][4];
#pragma unroll
  for (int i = 0; i < 4; ++i)
#pragma unroll
    for (int j = 0; j < 4; ++j) acc[i][j] = fz;
  const int NTK = K >> 6;

#define GSTAGE(ib, kt)                                                      \
  do {                                                                      \
    _Pragma("unroll") for (int c = 0; c < 4; ++c) {                         \
      int ra = c * 64 + w * 8 + srow;                                       \
      gload_lds16(A + (size_t)(m0 + ra) * K + (kt)*64 + schk * 8,           \
                  &lA[ib][c * 64 + w * 8][0]);                              \
    }                                                                       \
    _Pragma("unroll") for (int c = 0; c < 2; ++c) {                         \
      int rb = c * 64 + w * 8 + srow;                                       \
      gload_lds16(BT + (size_t)(n0 + rb) * K + (kt)*64 + schk * 8,          \
                  &lB[ib][c * 64 + w * 8][0]);                              \
    }                                                                       \
  } while (0)

  GSTAGE(0, 0);
  GSTAGE(1, 1);
  int ib = 0;
  for (int kt = 0; kt < NTK; ++kt) {
    if (kt + 1 < NTK)
      asm volatile("s_waitcnt vmcnt(6) lgkmcnt(0)" ::: "memory");
    else
      asm volatile("s_waitcnt vmcnt(0) lgkmcnt(0)" ::: "memory");
    __builtin_amdgcn_s_barrier();
    __builtin_amdgcn_sched_barrier(0);
    if (kt + 2 < NTK) {
      int ib2 = ib + 2;
      if (ib2 >= 3) ib2 -= 3;
      GSTAGE(ib2, kt + 2);
    }
#pragma unroll
    for (int kk = 0; kk < 2; ++kk) {
      s16x8 af[4], bf[4];
#pragma unroll
      for (int i = 0; i < 4; ++i)
        af[i] = *(const s16x8*)&lA[ib][wr * 64 + i * 16 + lrow]
                                     [(((kk << 2) + kgrp) ^ rchk) * 8];
#pragma unroll
      for (int j = 0; j < 4; ++j)
        bf[j] = *(const s16x8*)&lB[ib][wc * 64 + j * 16 + lrow]
                                     [(((kk << 2) + kgrp) ^ rchk) * 8];
      __builtin_amdgcn_s_setprio(1);
#pragma unroll
      for (int i = 0; i < 4; ++i)
#pragma unroll
        for (int j = 0; j < 4; ++j) acc[i][j] = MFMA(af[i], bf[j], acc[i][j]);
      __builtin_amdgcn_s_setprio(0);
    }
    ++ib;
    if (ib >= 3) ib = 0;
  }
#undef GSTAGE

#pragma unroll
  for (int i = 0; i < 4; ++i)
#pragma unroll
    for (int j = 0; j < 4; ++j)
#pragma unroll
      for (int r = 0; r < 4; ++r) {
        int row = m0 + wr * 64 + i * 16 + kgrp * 4 + r;
        int col = n0 + wc * 64 + j * 16 + lrow;
        float v = acc[i][j][r];
        if constexpr (sizeof(OT) == 2)
          C[(size_t)row * N + col] = __float2bfloat16(v);
        else
          C[(size_t)row * N + col] = v;
      }
}

// ---------------- flash attention (R6 structure + fused Q-RoPE) -----------
// 256 q-rows/block, 8 waves x 32 rows (2 row-frags), KVBLK=64, K/V double-
// buffered, ONE barrier per iteration. Swapped QK^T -> lane-local softmax,
// deferred l reduce, defer-max (T13). Q is read from the raw qkv buffer and
// RoPE'd in the prologue: each lane's chunks {kgrp*8,+32,+64,+96} are exactly
// self-paired under rotate_half (c <-> c+64), so rotation is in-lane.
// XOR chunk swizzle both sides (rule 21): K chunk^(row&15), V chunk^(d&7).

#define PSTR 72  // P row stride in elements: 144B = 16B-aligned
#define NT 48    // LT / 64
#define SCALE2 0.1275174335919605f  // scale * log2(e)

__global__ __launch_bounds__(512, 2) void flash_attn(
    const bf16* __restrict__ qkv, const float* __restrict__ cosT,
    const float* __restrict__ sinT, const bf16* __restrict__ Kf,
    const bf16* __restrict__ Vt, bf16* __restrict__ O) {
  __shared__ __attribute__((aligned(16))) bf16 Kl[2][64][128];      // 32 KB
  __shared__ __attribute__((aligned(16))) bf16 Vl[2][128][64];      // 32 KB
  __shared__ __attribute__((aligned(16))) bf16 P_lds[8][32][PSTR];  // 36 KB
  const int t = threadIdx.x, lane = t & 63, w = t >> 6;
  const int qb = blockIdx.x & 3, h = (blockIdx.x >> 2) & 15, b = blockIdx.x >> 6;
  const int hk = h >> 1;
  const int lrow = lane & 15, kgrp = lane >> 4;
  const bf16* Kp = Kf + (size_t)(b * NKV + hk) * LT * HD;
  const bf16* Vp = Vt + (size_t)(b * NKV + hk) * HD * LT;

  // prologue: load Q rows from qkv and apply RoPE in-register
  s16x8 qf[2][4];
#pragma unroll
  for (int f = 0; f < 2; ++f) {
    int srw_i = qb * 256 + w * 32 + f * 16 + lrow;
    const bf16* qrow = qkv + ((size_t)b * SS + srw_i) * QKVN + h * HD;
    s16x8 qr[4];
#pragma unroll
    for (int kd = 0; kd < 4; ++kd)
      qr[kd] = *(const s16x8*)&qrow[kd * 32 + kgrp * 8];
    const float* crow = cosT + srw_i * 64 + kgrp * 8;
    const float* srow = sinT + srw_i * 64 + kgrp * 8;
    float qv[4][8], cc[2][8], ssv[2][8];
#pragma unroll
    for (int kd = 0; kd < 4; ++kd)
#pragma unroll
      for (int j = 0; j < 8; ++j) qv[kd][j] = bf2f(qr[kd][j]);
#pragma unroll
    for (int g = 0; g < 2; ++g)
#pragma unroll
      for (int j = 0; j < 8; ++j) {
        cc[g][j] = crow[g * 32 + j];
        ssv[g][j] = srow[g * 32 + j];
      }
    bf16 o[4][8];
#pragma unroll
    for (int j = 0; j < 8; ++j) {
      o[0][j] = __float2bfloat16(qv[0][j] * cc[0][j] - qv[2][j] * ssv[0][j]);
      o[1][j] = __float2bfloat16(qv[1][j] * cc[1][j] - qv[3][j] * ssv[1][j]);
      o[2][j] = __float2bfloat16(qv[2][j] * cc[0][j] + qv[0][j] * ssv[0][j]);
      o[3][j] = __float2bfloat16(qv[3][j] * cc[1][j] + qv[1][j] * ssv[1][j]);
    }
#pragma unroll
    for (int kd = 0; kd < 4; ++kd) __builtin_memcpy(&qf[f][kd], o[kd], 16);
  }

  const f32x4 fz = {0.f, 0.f, 0.f, 0.f};
  f32x4 acc[2][8];
#pragma unroll
  for (int f = 0; f < 2; ++f)
#pragma unroll
    for (int i = 0; i < 8; ++i) acc[f][i] = fz;
  float m_[2] = {-1e30f, -1e30f}, l_[2] = {0.f, 0.f};

#define STAGE_K(buf, l0)                                                        \
  do {                                                                          \
    _Pragma("unroll") for (int c = 0; c < 2; ++c) {                             \
      int row = w * 8 + c * 4 + (lane >> 4);                                    \
      gload_lds16(Kp + (size_t)((l0) + row) * HD + ((lane & 15) ^ (row & 15)) * 8, \
                  &Kl[buf][w * 8 + c * 4][0]);                                  \
    }                                                                           \
  } while (0)
#define STAGE_V(buf, l0)                                                        \
  do {                                                                          \
    _Pragma("unroll") for (int c = 0; c < 2; ++c) {                             \
      int d = w * 16 + c * 8 + (lane >> 3);                                     \
      gload_lds16(Vp + (size_t)d * LT + (l0) + ((lane & 7) ^ (d & 7)) * 8,      \
                  &Vl[buf][w * 16 + c * 8][0]);                                 \
    }                                                                           \
  } while (0)

  STAGE_K(0, 0);
  STAGE_V(0, 0);
  __syncthreads();

  for (int tt = 0; tt < NT; ++tt) {
    const int cur = tt & 1;
    if (tt + 1 < NT) {
      STAGE_K(cur ^ 1, (tt + 1) * 64);
      STAGE_V(cur ^ 1, (tt + 1) * 64);
    }

    f32x4 sc[2][4];
#pragma unroll
    for (int f = 0; f < 2; ++f)
#pragma unroll
      for (int cf = 0; cf < 4; ++cf) sc[f][cf] = fz;
#pragma unroll
    for (int cf = 0; cf < 4; ++cf)
#pragma unroll
      for (int kd = 0; kd < 4; ++kd) {
        s16x8 kb =
            *(const s16x8*)&Kl[cur][cf * 16 + lrow][((kd * 4 + kgrp) ^ lrow) * 8];
#pragma unroll
        for (int f = 0; f < 2; ++f) sc[f][cf] = MFMA(kb, qf[f][kd], sc[f][cf]);
      }

    float mxv[2];
#pragma unroll
    for (int f = 0; f < 2; ++f) {
      float a0 = fmaxf(fmaxf(sc[f][0][0], sc[f][0][1]),
                       fmaxf(sc[f][0][2], sc[f][0][3]));
      float a1 = fmaxf(fmaxf(sc[f][1][0], sc[f][1][1]),
                       fmaxf(sc[f][1][2], sc[f][1][3]));
      float a2 = fmaxf(fmaxf(sc[f][2][0], sc[f][2][1]),
                       fmaxf(sc[f][2][2], sc[f][2][3]));
      float a3 = fmaxf(fmaxf(sc[f][3][0], sc[f][3][1]),
                       fmaxf(sc[f][3][2], sc[f][3][3]));
      float mx = fmaxf(fmaxf(a0, a1), fmaxf(a2, a3)) * SCALE2;
      mx = fmaxf(mx, __shfl_xor(mx, 16, 64));
      mx = fmaxf(mx, __shfl_xor(mx, 32, 64));
      mxv[f] = mx;
    }
    bool nb = (mxv[0] > m_[0] + 8.f) || (mxv[1] > m_[1] + 8.f);
    if (__any(nb)) {
#pragma unroll
      for (int f = 0; f < 2; ++f) {
        float mn = fmaxf(m_[f], mxv[f]);
        float so = exp2f(m_[f] - mn);
        m_[f] = mn;
        l_[f] *= so;
        float sob[4];
#pragma unroll
        for (int r = 0; r < 4; ++r) sob[r] = __shfl(so, kgrp * 4 + r, 16);
#pragma unroll
        for (int nd = 0; nd < 8; ++nd)
#pragma unroll
          for (int r = 0; r < 4; ++r) acc[f][nd][r] *= sob[r];
      }
    }
#pragma unroll
    for (int f = 0; f < 2; ++f) {
      float lp = 0.f;
#pragma unroll
      for (int cf = 0; cf < 4; ++cf) {
        bf16 pk[4];
#pragma unroll
        for (int r = 0; r < 4; ++r) {
          float p = exp2f(sc[f][cf][r] * SCALE2 - m_[f]);
          lp += p;
          pk[r] = __float2bfloat16(p);
        }
        __builtin_memcpy((void*)&P_lds[w][f * 16 + lrow][cf * 16 + kgrp * 4], pk, 8);
      }
      l_[f] += lp;
    }

    s16x8 pa[2][2];
#pragma unroll
    for (int f = 0; f < 2; ++f)
#pragma unroll
      for (int kc = 0; kc < 2; ++kc)
        pa[f][kc] = *(const s16x8*)&P_lds[w][f * 16 + lrow][kc * 32 + kgrp * 8];

#pragma unroll
    for (int nd = 0; nd < 8; ++nd)
#pragma unroll
      for (int kc = 0; kc < 2; ++kc) {
        s16x8 vb = *(const s16x8*)&Vl[cur][nd * 16 + lrow]
                                     [((kc * 4 + kgrp) ^ (lrow & 7)) * 8];
#pragma unroll
        for (int f = 0; f < 2; ++f) acc[f][nd] = MFMA(pa[f][kc], vb, acc[f][nd]);
      }
    __syncthreads();  // drains stage(tt+1) DMA; protects bufs for next iter
  }
#undef STAGE_K
#undef STAGE_V

  float li[2][4];
#pragma unroll
  for (int f = 0; f < 2; ++f) {
    float lv = l_[f];
    lv += __shfl_xor(lv, 16, 64);
    lv += __shfl_xor(lv, 32, 64);
#pragma unroll
    for (int r = 0; r < 4; ++r) li[f][r] = 1.f / __shfl(lv, kgrp * 4 + r, 16);
  }
#pragma unroll
  for (int f = 0; f < 2; ++f)
#pragma unroll
    for (int nd = 0; nd < 8; ++nd)
#pragma unroll
      for (int r = 0; r < 4; ++r) {
        int row = qb * 256 + w * 32 + f * 16 + kgrp * 4 + r;
        O[((size_t)b * SS + row) * 2048 + h * HD + nd * 16 + lrow] =
            __float2bfloat16(acc[f][nd][r] * li[f][r]);
      }
}

// ---------------- launch ----------------

extern "C" void kernel_launch(void* const* d_in, const int* in_sizes, int n_in,
                              void* d_out, int out_size, void* d_ws, size_t ws_size,
                              hipStream_t stream) {
  const float* hs = (const float*)d_in[0];
  const float* Wqkv = (const float*)d_in[1];
  const float* Wo = (const float*)d_in[2];
  const float* ctx_k = (const float*)d_in[3];
  const float* ctx_v = (const float*)d_in[4];
  const int* pid = (const int*)d_in[5];
  float* out = (float*)d_out;
  char* ws = (char*)d_ws;

  bf16* Hb = (bf16*)(ws);                      // 16.78 MB (reused as attn_out)
  bf16* WqT = (bf16*)(ws + 16777216);          // 16.78 MB
  bf16* WoT = (bf16*)(ws + 33554432);          // 8.39 MB
  bf16* qkv = (bf16*)(ws + 41943040);          // 33.55 MB
  bf16* Kfull = (bf16*)(ws + 92274688);        // 25.17 MB
  bf16* Vt = (bf16*)(ws + 117440512);          // 25.17 MB
  float* cosT = (float*)(ws + 142606336);      // 256 KB
  float* sinT = (float*)(ws + 142606336 + 262144);
  bf16* attn = Hb;  // alias: Hb dead after QKV GEMM

  prep1<<<P1_CV, 256, 0, stream>>>(hs, Wqkv, Wo, ctx_k, ctx_v, pid, Hb, WqT, WoT,
                                   Kfull, Vt, cosT, sinT);
  gemm_bt<bf16><<<dim3(QKVN / 128, MROWS / 256), 512, 0, stream>>>(
      Hb, WqT, qkv, MROWS, QKVN, HID);
  prep2<<<12288, 256, 0, stream>>>(qkv, cosT, sinT, Kfull, Vt);
  flash_attn<<<256, 512, 0, stream>>>(qkv, cosT, sinT, Kfull, Vt, attn);
  gemm_bt<float><<<dim3(2048 / 128, MROWS / 256), 512, 0, stream>>>(
      attn, WoT, out, MROWS, 2048, HID);
}

// Round 14
// 325.753 us; speedup vs baseline: 1.1060x; 1.0439x over previous
//
#include <hip/hip_runtime.h>
#include <hip/hip_bf16.h>
#include <stdint.h>

#define NH 16
#define NKV 8
#define HD 128
#define BB 4
#define SS 1024
#define CTXL 2048
#define LT 3072
#define HID 2048
#define QKVN 4096
#define MROWS 4096

typedef __hip_bfloat16 bf16;
using f32x4 = __attribute__((ext_vector_type(4))) float;
using s16x8 = __attribute__((ext_vector_type(8))) short;

#define MFMA(a, b, c) __builtin_amdgcn_mfma_f32_16x16x32_bf16((a), (b), (c), 0, 0, 0)

__device__ __forceinline__ void gload_lds16(const void* g, void* l) {
  __builtin_amdgcn_global_load_lds((const __attribute__((address_space(1))) void*)g,
                                   (__attribute__((address_space(3))) void*)l, 16, 0, 0);
}

__device__ __forceinline__ void store_bf8(bf16* dst, const float* f) {
  bf16 tmp[8];
#pragma unroll
  for (int j = 0; j < 8; ++j) tmp[j] = __float2bfloat16(f[j]);
  __builtin_memcpy((void*)dst, (const void*)tmp, 16);
}

__device__ __forceinline__ float bf2f(short x) {
  unsigned int u = ((unsigned int)(unsigned short)x) << 16;
  float f;
  __builtin_memcpy(&f, &u, 4);
  return f;
}

// ---------------- prep1: cvt + weight transposes + rope table + ctx K/V ----
#define P1_CVT 4096
#define P1_WQ (P1_CVT + 8192)
#define P1_WO (P1_WQ + 4096)
#define P1_RT (P1_WO + 256)
#define P1_CK (P1_RT + 4096)
#define P1_CV (P1_CK + 8192)

__global__ void prep1(const float* __restrict__ hs, const float* __restrict__ Wqkv,
                      const float* __restrict__ Wo, const float* __restrict__ ck,
                      const float* __restrict__ cv, const int* __restrict__ pid,
                      bf16* __restrict__ Hb, bf16* __restrict__ WqT,
                      bf16* __restrict__ WoT, bf16* __restrict__ Kf,
                      bf16* __restrict__ Vt, float* __restrict__ cosT,
                      float* __restrict__ sinT) {
  __shared__ float tile[32][33];
  const int blk = blockIdx.x, thr = threadIdx.x;
  if (blk < P1_CVT) {
    size_t tid = (size_t)blk * 256 + thr;
    const float4* p = (const float4*)(hs + tid * 8);
    float4 a = p[0], b = p[1];
    float f[8] = {a.x, a.y, a.z, a.w, b.x, b.y, b.z, b.w};
    store_bf8(Hb + tid * 8, f);
  } else if (blk < P1_WQ) {
    int j = blk - P1_CVT;
    int c0 = (j & 127) * 32, r0 = (j >> 7) * 32;  // R=2048 C=4096
    int tx = thr & 31, ty = thr >> 5;
#pragma unroll
    for (int i = 0; i < 32; i += 8)
      tile[ty + i][tx] = Wqkv[(size_t)(r0 + ty + i) * QKVN + c0 + tx];
    __syncthreads();
#pragma unroll
    for (int i = 0; i < 32; i += 8)
      WqT[(size_t)(c0 + ty + i) * HID + r0 + tx] = __float2bfloat16(tile[tx][ty + i]);
  } else if (blk < P1_WO) {
    int j = blk - P1_WQ;
    int c0 = (j & 63) * 32, r0 = (j >> 6) * 32;  // 2048x2048
    int tx = thr & 31, ty = thr >> 5;
#pragma unroll
    for (int i = 0; i < 32; i += 8)
      tile[ty + i][tx] = Wo[(size_t)(r0 + ty + i) * 2048 + c0 + tx];
    __syncthreads();
#pragma unroll
    for (int i = 0; i < 32; i += 8)
      WoT[(size_t)(c0 + ty + i) * 2048 + r0 + tx] = __float2bfloat16(tile[tx][ty + i]);
  } else if (blk < P1_RT) {
    int tid = (blk - P1_WO) * 256 + thr;  // S*64
    int j = tid & 63, s = tid >> 6;
    int sec = (j < 8) ? 0 : (j < 16) ? 1 : (j < 40) ? 2 : 3;
    float pos = (float)pid[sec * SS + s];
    float inv = __expf(-(float)j * 0.14391156831212787f);  // ln(10000)/64
    float a = pos * inv;
    cosT[tid] = cosf(a);
    sinT[tid] = sinf(a);
  } else if (blk < P1_CK) {
    int tid = (blk - P1_RT) * 256 + thr;
    int d8 = tid & 15, l = (tid >> 4) & 2047, h = (tid >> 15) & 7, b = tid >> 18;
    const float* s = ck + (((size_t)b * CTXL + l) * NKV + h) * HD + d8 * 8;
    const float4* p = (const float4*)s;
    float4 a = p[0], bb = p[1];
    float f[8] = {a.x, a.y, a.z, a.w, bb.x, bb.y, bb.z, bb.w};
    store_bf8(Kf + (((size_t)(b * NKV + h)) * LT + l) * HD + d8 * 8, f);
  } else {
    int j = blk - P1_CK;
    int l0 = (j & 63) * 32, d0 = ((j >> 6) & 3) * 32;
    int bz = j >> 8, b = bz >> 3, h = bz & 7;
    int tx = thr & 31, ty = thr >> 5;
#pragma unroll
    for (int i = 0; i < 32; i += 8)
      tile[ty + i][tx] =
          cv[(((size_t)b * CTXL + l0 + ty + i) * NKV + h) * HD + d0 + tx];
    __syncthreads();
#pragma unroll
    for (int i = 0; i < 32; i += 8)
      Vt[(((size_t)(b * NKV + h)) * HD + d0 + ty + i) * LT + l0 + tx] =
          __float2bfloat16(tile[tx][ty + i]);
  }
}

// ---------------- prep2: rope_k + vt_from_qkv (both read qkv) --------------
__global__ void prep2(const bf16* __restrict__ qkv, const float* __restrict__ cosT,
                      const float* __restrict__ sinT, bf16* __restrict__ Kf,
                      bf16* __restrict__ Vt) {
  __shared__ float tile[32][33];
  const int blk = blockIdx.x, thr = threadIdx.x;
  if (blk < 8192) {
    int tid = blk * 256 + thr;
    int j = tid & 63, h = (tid >> 6) & 7, s = (tid >> 9) & 1023, b = tid >> 19;
    const bf16* src = qkv + ((size_t)b * SS + s) * QKVN + 2048 + h * HD;
    float x1 = __bfloat162float(src[j]), x2 = __bfloat162float(src[j + 64]);
    float c = cosT[s * 64 + j], sn = sinT[s * 64 + j];
    bf16* dst = Kf + (((size_t)(b * NKV + h)) * LT + CTXL + s) * HD;
    dst[j] = __float2bfloat16(x1 * c - x2 * sn);
    dst[j + 64] = __float2bfloat16(x2 * c + x1 * sn);
  } else {
    int j = blk - 8192;
    int s0 = (j & 31) * 32, d0 = ((j >> 5) & 3) * 32;
    int bz = j >> 7, b = bz >> 3, h = bz & 7;
    int tx = thr & 31, ty = thr >> 5;
#pragma unroll
    for (int i = 0; i < 32; i += 8)
      tile[ty + i][tx] = __bfloat162float(
          qkv[((size_t)b * SS + s0 + ty + i) * QKVN + 3072 + h * HD + d0 + tx]);
    __syncthreads();
#pragma unroll
    for (int i = 0; i < 32; i += 8)
      Vt[(((size_t)(b * NKV + h)) * HD + d0 + ty + i) * LT + CTXL + s0 + tx] =
          __float2bfloat16(tile[tx][ty + i]);
  }
}

// ---------------- GEMM: C[M][N] = A[M][K] * BT[N][K]^T ----------------
template <typename OT>
__global__ __launch_bounds__(512, 1) void gemm_bt(const bf16* __restrict__ A,
                                                  const bf16* __restrict__ BT,
                                                  OT* __restrict__ C, int M, int N,
                                                  int K) {
  __shared__ __attribute__((aligned(16))) bf16 lA[3][256][64];  // 96 KB
  __shared__ __attribute__((aligned(16))) bf16 lB[3][128][64];  // 48 KB
  const int t = threadIdx.x;
  const int lane = t & 63, w = t >> 6;
  const int wr = w >> 1, wc = w & 1;
  const int lrow = lane & 15, kgrp = lane >> 4;
  const int rchk = lrow & 7;
  const int lin = blockIdx.y * gridDim.x + blockIdx.x;
  const int qq = (gridDim.x * gridDim.y) >> 3;
  const int swz = (lin & 7) * qq + (lin >> 3);
  const int bx = swz % gridDim.x, by = swz / gridDim.x;
  const int m0 = by * 256, n0 = bx * 128;
  const int srow = lane >> 3;
  const int schk = (lane & 7) ^ srow;
  const f32x4 fz = {0.f, 0.f, 0.f, 0.f};
  f32x4 acc[4][4];
#pragma unroll
  for (int i = 0; i < 4; ++i)
#pragma unroll
    for (int j = 0; j < 4; ++j) acc[i][j] = fz;
  const int NTK = K >> 6;

#define GSTAGE(ib, kt)                                                      \
  do {                                                                      \
    _Pragma("unroll") for (int c = 0; c < 4; ++c) {                         \
      int ra = c * 64 + w * 8 + srow;                                       \
      gload_lds16(A + (size_t)(m0 + ra) * K + (kt)*64 + schk * 8,           \
                  &lA[ib][c * 64 + w * 8][0]);                              \
    }                                                                       \
    _Pragma("unroll") for (int c = 0; c < 2; ++c) {                         \
      int rb = c * 64 + w * 8 + srow;                                       \
      gload_lds16(BT + (size_t)(n0 + rb) * K + (kt)*64 + schk * 8,          \
                  &lB[ib][c * 64 + w * 8][0]);                              \
    }                                                                       \
  } while (0)

  GSTAGE(0, 0);
  GSTAGE(1, 1);
  int ib = 0;
  for (int kt = 0; kt < NTK; ++kt) {
    if (kt + 1 < NTK)
      asm volatile("s_waitcnt vmcnt(6) lgkmcnt(0)" ::: "memory");
    else
      asm volatile("s_waitcnt vmcnt(0) lgkmcnt(0)" ::: "memory");
    __builtin_amdgcn_s_barrier();
    __builtin_amdgcn_sched_barrier(0);
    if (kt + 2 < NTK) {
      int ib2 = ib + 2;
      if (ib2 >= 3) ib2 -= 3;
      GSTAGE(ib2, kt + 2);
    }
#pragma unroll
    for (int kk = 0; kk < 2; ++kk) {
      s16x8 af[4], bf[4];
#pragma unroll
      for (int i = 0; i < 4; ++i)
        af[i] = *(const s16x8*)&lA[ib][wr * 64 + i * 16 + lrow]
                                     [(((kk << 2) + kgrp) ^ rchk) * 8];
#pragma unroll
      for (int j = 0; j < 4; ++j)
        bf[j] = *(const s16x8*)&lB[ib][wc * 64 + j * 16 + lrow]
                                     [(((kk << 2) + kgrp) ^ rchk) * 8];
      __builtin_amdgcn_s_setprio(1);
#pragma unroll
      for (int i = 0; i < 4; ++i)
#pragma unroll
        for (int j = 0; j < 4; ++j) acc[i][j] = MFMA(af[i], bf[j], acc[i][j]);
      __builtin_amdgcn_s_setprio(0);
    }
    ++ib;
    if (ib >= 3) ib = 0;
  }
#undef GSTAGE

#pragma unroll
  for (int i = 0; i < 4; ++i)
#pragma unroll
    for (int j = 0; j < 4; ++j)
#pragma unroll
      for (int r = 0; r < 4; ++r) {
        int row = m0 + wr * 64 + i * 16 + kgrp * 4 + r;
        int col = n0 + wc * 64 + j * 16 + lrow;
        float v = acc[i][j][r];
        if constexpr (sizeof(OT) == 2)
          C[(size_t)row * N + col] = __float2bfloat16(v);
        else
          C[(size_t)row * N + col] = v;
      }
}

// ---------------- flash attention (R6 core, KVBLK=128, XCD panel swizzle) --
// 256 q-rows/block, 8 waves x 32 rows, KVBLK=128 -> 24 iterations (halves
// shfl trees / loop overhead; inverse of R10's measured-bad direction).
// K double-buffered [2][128][128]; V single-buffered [128][128], staged at
// iter top, landed at barrier #1, consumed by PV after. PV in two kv-halves
// reusing the per-wave P buffer (in-wave DS ordering makes reuse safe).
// XCD swizzle: 8 blocks sharing a (b,hk) panel get ids == same mod 8.
// Fused Q-RoPE prologue. Swapped QK^T, lane-local softmax, defer-max (T13).
// XOR chunk swizzle both sides (rule 21): K/V chunk^(row&15).

#define PSTR 72  // P row stride in elements: 144B = 16B-aligned
#define KVB 128
#define NTT 24   // LT / 128
#define SCALE2 0.1275174335919605f  // scale * log2(e)

__global__ __launch_bounds__(512, 2) void flash_attn(
    const bf16* __restrict__ qkv, const float* __restrict__ cosT,
    const float* __restrict__ sinT, const bf16* __restrict__ Kf,
    const bf16* __restrict__ Vt, bf16* __restrict__ O) {
  __shared__ __attribute__((aligned(16))) bf16 Kl[2][128][128];     // 64 KB
  __shared__ __attribute__((aligned(16))) bf16 Vl[128][128];        // 32 KB
  __shared__ __attribute__((aligned(16))) bf16 P_lds[8][32][PSTR];  // 36 KB
  const int t = threadIdx.x, lane = t & 63, w = t >> 6;
  // XCD panel swizzle (bijective): b=id>>6, hk=id&7, h=(hk<<1)|bit5, qb=bits3-4
  const int id = blockIdx.x;
  const int b = id >> 6, hk = id & 7;
  const int h = (hk << 1) | ((id >> 5) & 1);
  const int qb = (id >> 3) & 3;
  const int lrow = lane & 15, kgrp = lane >> 4;
  const bf16* Kp = Kf + (size_t)(b * NKV + hk) * LT * HD;
  const bf16* Vp = Vt + (size_t)(b * NKV + hk) * HD * LT;

  // prologue: load Q rows from qkv and apply RoPE in-register
  s16x8 qf[2][4];
#pragma unroll
  for (int f = 0; f < 2; ++f) {
    int srw_i = qb * 256 + w * 32 + f * 16 + lrow;
    const bf16* qrow = qkv + ((size_t)b * SS + srw_i) * QKVN + h * HD;
    s16x8 qr[4];
#pragma unroll
    for (int kd = 0; kd < 4; ++kd)
      qr[kd] = *(const s16x8*)&qrow[kd * 32 + kgrp * 8];
    const float* crow = cosT + srw_i * 64 + kgrp * 8;
    const float* srow = sinT + srw_i * 64 + kgrp * 8;
    float qv[4][8], cc[2][8], ssv[2][8];
#pragma unroll
    for (int kd = 0; kd < 4; ++kd)
#pragma unroll
      for (int j = 0; j < 8; ++j) qv[kd][j] = bf2f(qr[kd][j]);
#pragma unroll
    for (int g = 0; g < 2; ++g)
#pragma unroll
      for (int j = 0; j < 8; ++j) {
        cc[g][j] = crow[g * 32 + j];
        ssv[g][j] = srow[g * 32 + j];
      }
    bf16 o[4][8];
#pragma unroll
    for (int j = 0; j < 8; ++j) {
      o[0][j] = __float2bfloat16(qv[0][j] * cc[0][j] - qv[2][j] * ssv[0][j]);
      o[1][j] = __float2bfloat16(qv[1][j] * cc[1][j] - qv[3][j] * ssv[1][j]);
      o[2][j] = __float2bfloat16(qv[2][j] * cc[0][j] + qv[0][j] * ssv[0][j]);
      o[3][j] = __float2bfloat16(qv[3][j] * cc[1][j] + qv[1][j] * ssv[1][j]);
    }
#pragma unroll
    for (int kd = 0; kd < 4; ++kd) __builtin_memcpy(&qf[f][kd], o[kd], 16);
  }

  const f32x4 fz = {0.f, 0.f, 0.f, 0.f};
  f32x4 acc[2][8];
#pragma unroll
  for (int f = 0; f < 2; ++f)
#pragma unroll
    for (int i = 0; i < 8; ++i) acc[f][i] = fz;
  float m_[2] = {-1e30f, -1e30f}, l_[2] = {0.f, 0.f};

  // staging (8 waves, 512 threads, 4 loads/thread per tile)
#define STAGE_K(buf, l0)                                                        \
  do {                                                                          \
    _Pragma("unroll") for (int c = 0; c < 4; ++c) {                             \
      int row = w * 16 + c * 4 + (lane >> 4);                                   \
      gload_lds16(Kp + (size_t)((l0) + row) * HD + ((lane & 15) ^ (row & 15)) * 8, \
                  &Kl[buf][w * 16 + c * 4][0]);                                 \
    }                                                                           \
  } while (0)
#define STAGE_V(l0)                                                             \
  do {                                                                          \
    _Pragma("unroll") for (int c = 0; c < 4; ++c) {                             \
      int d = w * 16 + c * 4 + (lane >> 4);                                     \
      gload_lds16(Vp + (size_t)d * LT + (l0) + ((lane & 15) ^ (d & 15)) * 8,    \
                  &Vl[w * 16 + c * 4][0]);                                      \
    }                                                                           \
  } while (0)

  STAGE_K(0, 0);
  __syncthreads();

  for (int tt = 0; tt < NTT; ++tt) {
    const int cur = tt & 1;
    STAGE_V(tt * KVB);
    if (tt + 1 < NTT) STAGE_K(cur ^ 1, (tt + 1) * KVB);

    // QK^T swapped: sc[f][cf][r] = score for q-row (lane&15) of frag f,
    // kv = cf*16 + kgrp*4 + r  (cf 0..7 over 128 kv)
    f32x4 sc[2][8];
#pragma unroll
    for (int f = 0; f < 2; ++f)
#pragma unroll
      for (int cf = 0; cf < 8; ++cf) sc[f][cf] = fz;
#pragma unroll
    for (int cf = 0; cf < 8; ++cf)
#pragma unroll
      for (int kd = 0; kd < 4; ++kd) {
        s16x8 kb =
            *(const s16x8*)&Kl[cur][cf * 16 + lrow][((kd * 4 + kgrp) ^ lrow) * 8];
#pragma unroll
        for (int f = 0; f < 2; ++f) sc[f][cf] = MFMA(kb, qf[f][kd], sc[f][cf]);
      }

    // lane-local max over 32 scores, then 2 wide shfls
    float mxv[2];
#pragma unroll
    for (int f = 0; f < 2; ++f) {
      float mx = sc[f][0][0];
#pragma unroll
      for (int cf = 0; cf < 8; ++cf)
#pragma unroll
        for (int r = 0; r < 4; ++r) mx = fmaxf(mx, sc[f][cf][r]);
      mx *= SCALE2;
      mx = fmaxf(mx, __shfl_xor(mx, 16, 64));
      mx = fmaxf(mx, __shfl_xor(mx, 32, 64));
      mxv[f] = mx;
    }
    bool nb = (mxv[0] > m_[0] + 8.f) || (mxv[1] > m_[1] + 8.f);
    if (__any(nb)) {
#pragma unroll
      for (int f = 0; f < 2; ++f) {
        float mn = fmaxf(m_[f], mxv[f]);
        float so = exp2f(m_[f] - mn);
        m_[f] = mn;
        l_[f] *= so;
        float sob[4];
#pragma unroll
        for (int r = 0; r < 4; ++r) sob[r] = __shfl(so, kgrp * 4 + r, 16);
#pragma unroll
        for (int nd = 0; nd < 8; ++nd)
#pragma unroll
          for (int r = 0; r < 4; ++r) acc[f][nd][r] *= sob[r];
      }
    }

    // P half A (kv 0..63): pack + write, lp partial
    float lp[2] = {0.f, 0.f};
#pragma unroll
    for (int f = 0; f < 2; ++f)
#pragma unroll
      for (int cf = 0; cf < 4; ++cf) {
        bf16 pk[4];
#pragma unroll
        for (int r = 0; r < 4; ++r) {
          float p = exp2f(sc[f][cf][r] * SCALE2 - m_[f]);
          lp[f] += p;
          pk[r] = __float2bfloat16(p);
        }
        __builtin_memcpy((void*)&P_lds[w][f * 16 + lrow][cf * 16 + kgrp * 4], pk, 8);
      }
    s16x8 pa[2][2];
#pragma unroll
    for (int f = 0; f < 2; ++f)
#pragma unroll
      for (int kc = 0; kc < 2; ++kc)
        pa[f][kc] = *(const s16x8*)&P_lds[w][f * 16 + lrow][kc * 32 + kgrp * 8];

    __syncthreads();  // barrier #1: V(tt) + K(tt+1) DMA landed

    // PV half A (kv 0..63): V chunk = kc*4+kgrp, swizzled ^row
#pragma unroll
    for (int nd = 0; nd < 8; ++nd)
#pragma unroll
      for (int kc = 0; kc < 2; ++kc) {
        s16x8 vb = *(const s16x8*)&Vl[nd * 16 + lrow]
                                     [((kc * 4 + kgrp) ^ lrow) * 8];
#pragma unroll
        for (int f = 0; f < 2; ++f) acc[f][nd] = MFMA(pa[f][kc], vb, acc[f][nd]);
      }

    // P half B (kv 64..127): reuse P buffer (in-wave DS ordering after reads)
#pragma unroll
    for (int f = 0; f < 2; ++f)
#pragma unroll
      for (int cf = 4; cf < 8; ++cf) {
        bf16 pk[4];
#pragma unroll
        for (int r = 0; r < 4; ++r) {
          float p = exp2f(sc[f][cf][r] * SCALE2 - m_[f]);
          lp[f] += p;
          pk[r] = __float2bfloat16(p);
        }
        __builtin_memcpy(
            (void*)&P_lds[w][f * 16 + lrow][(cf - 4) * 16 + kgrp * 4], pk, 8);
      }
#pragma unroll
    for (int f = 0; f < 2; ++f) {
      l_[f] += lp[f];
#pragma unroll
      for (int kc = 0; kc < 2; ++kc)
        pa[f][kc] = *(const s16x8*)&P_lds[w][f * 16 + lrow][kc * 32 + kgrp * 8];
    }
    // PV half B (kv 64..127): V chunk = 8 + kc*4+kgrp, swizzled ^row
#pragma unroll
    for (int nd = 0; nd < 8; ++nd)
#pragma unroll
      for (int kc = 0; kc < 2; ++kc) {
        s16x8 vb = *(const s16x8*)&Vl[nd * 16 + lrow]
                                     [((8 + kc * 4 + kgrp) ^ lrow) * 8];
#pragma unroll
        for (int f = 0; f < 2; ++f) acc[f][nd] = MFMA(pa[f][kc], vb, acc[f][nd]);
      }
    __syncthreads();  // barrier #2: protect Vl / Kl before next iter staging
  }
#undef STAGE_K
#undef STAGE_V

  float li[2][4];
#pragma unroll
  for (int f = 0; f < 2; ++f) {
    float lv = l_[f];
    lv += __shfl_xor(lv, 16, 64);
    lv += __shfl_xor(lv, 32, 64);
#pragma unroll
    for (int r = 0; r < 4; ++r) li[f][r] = 1.f / __shfl(lv, kgrp * 4 + r, 16);
  }
#pragma unroll
  for (int f = 0; f < 2; ++f)
#pragma unroll
    for (int nd = 0; nd < 8; ++nd)
#pragma unroll
      for (int r = 0; r < 4; ++r) {
        int row = qb * 256 + w * 32 + f * 16 + kgrp * 4 + r;
        O[((size_t)b * SS + row) * 2048 + h * HD + nd * 16 + lrow] =
            __float2bfloat16(acc[f][nd][r] * li[f][r]);
      }
}

// ---------------- launch ----------------

extern "C" void kernel_launch(void* const* d_in, const int* in_sizes, int n_in,
                              void* d_out, int out_size, void* d_ws, size_t ws_size,
                              hipStream_t stream) {
  const float* hs = (const float*)d_in[0];
  const float* Wqkv = (const float*)d_in[1];
  const float* Wo = (const float*)d_in[2];
  const float* ctx_k = (const float*)d_in[3];
  const float* ctx_v = (const float*)d_in[4];
  const int* pid = (const int*)d_in[5];
  float* out = (float*)d_out;
  char* ws = (char*)d_ws;

  bf16* Hb = (bf16*)(ws);                      // 16.78 MB (reused as attn_out)
  bf16* WqT = (bf16*)(ws + 16777216);          // 16.78 MB
  bf16* WoT = (bf16*)(ws + 33554432);          // 8.39 MB
  bf16* qkv = (bf16*)(ws + 41943040);          // 33.55 MB
  bf16* Kfull = (bf16*)(ws + 92274688);        // 25.17 MB
  bf16* Vt = (bf16*)(ws + 117440512);          // 25.17 MB
  float* cosT = (float*)(ws + 142606336);      // 256 KB
  float* sinT = (float*)(ws + 142606336 + 262144);
  bf16* attn = Hb;  // alias: Hb dead after QKV GEMM

  prep1<<<P1_CV, 256, 0, stream>>>(hs, Wqkv, Wo, ctx_k, ctx_v, pid, Hb, WqT, WoT,
                                   Kfull, Vt, cosT, sinT);
  gemm_bt<bf16><<<dim3(QKVN / 128, MROWS / 256), 512, 0, stream>>>(
      Hb, WqT, qkv, MROWS, QKVN, HID);
  prep2<<<12288, 256, 0, stream>>>(qkv, cosT, sinT, Kfull, Vt);
  flash_attn<<<256, 512, 0, stream>>>(qkv, cosT, sinT, Kfull, Vt, attn);
  gemm_bt<float><<<dim3(2048 / 128, MROWS / 256), 512, 0, stream>>>(
      attn, WoT, out, MROWS, 2048, HID);
}

// Round 15
// 317.664 us; speedup vs baseline: 1.1341x; 1.0255x over previous
//
#include <hip/hip_runtime.h>
#include <hip/hip_bf16.h>
#include <stdint.h>

#define NH 16
#define NKV 8
#define HD 128
#define BB 4
#define SS 1024
#define CTXL 2048
#define LT 3072
#define HID 2048
#define QKVN 4096
#define MROWS 4096

typedef __hip_bfloat16 bf16;
using f32x4 = __attribute__((ext_vector_type(4))) float;
using s16x8 = __attribute__((ext_vector_type(8))) short;

#define MFMA(a, b, c) __builtin_amdgcn_mfma_f32_16x16x32_bf16((a), (b), (c), 0, 0, 0)

__device__ __forceinline__ void gload_lds16(const void* g, void* l) {
  __builtin_amdgcn_global_load_lds((const __attribute__((address_space(1))) void*)g,
                                   (__attribute__((address_space(3))) void*)l, 16, 0, 0);
}

__device__ __forceinline__ void store_bf8(bf16* dst, const float* f) {
  bf16 tmp[8];
#pragma unroll
  for (int j = 0; j < 8; ++j) tmp[j] = __float2bfloat16(f[j]);
  __builtin_memcpy((void*)dst, (const void*)tmp, 16);
}

__device__ __forceinline__ float bf2f(short x) {
  unsigned int u = ((unsigned int)(unsigned short)x) << 16;
  float f;
  __builtin_memcpy(&f, &u, 4);
  return f;
}

// ---------------- prep1: cvt + weight transposes + rope table + ctx K/V ----
#define P1_CVT 4096
#define P1_WQ (P1_CVT + 8192)
#define P1_WO (P1_WQ + 4096)
#define P1_RT (P1_WO + 256)
#define P1_CK (P1_RT + 4096)
#define P1_CV (P1_CK + 8192)

__global__ void prep1(const float* __restrict__ hs, const float* __restrict__ Wqkv,
                      const float* __restrict__ Wo, const float* __restrict__ ck,
                      const float* __restrict__ cv, const int* __restrict__ pid,
                      bf16* __restrict__ Hb, bf16* __restrict__ WqT,
                      bf16* __restrict__ WoT, bf16* __restrict__ Kf,
                      bf16* __restrict__ Vt, float* __restrict__ cosT,
                      float* __restrict__ sinT) {
  __shared__ float tile[32][33];
  const int blk = blockIdx.x, thr = threadIdx.x;
  if (blk < P1_CVT) {
    size_t tid = (size_t)blk * 256 + thr;
    const float4* p = (const float4*)(hs + tid * 8);
    float4 a = p[0], b = p[1];
    float f[8] = {a.x, a.y, a.z, a.w, b.x, b.y, b.z, b.w};
    store_bf8(Hb + tid * 8, f);
  } else if (blk < P1_WQ) {
    int j = blk - P1_CVT;
    int c0 = (j & 127) * 32, r0 = (j >> 7) * 32;  // R=2048 C=4096
    int tx = thr & 31, ty = thr >> 5;
#pragma unroll
    for (int i = 0; i < 32; i += 8)
      tile[ty + i][tx] = Wqkv[(size_t)(r0 + ty + i) * QKVN + c0 + tx];
    __syncthreads();
#pragma unroll
    for (int i = 0; i < 32; i += 8)
      WqT[(size_t)(c0 + ty + i) * HID + r0 + tx] = __float2bfloat16(tile[tx][ty + i]);
  } else if (blk < P1_WO) {
    int j = blk - P1_WQ;
    int c0 = (j & 63) * 32, r0 = (j >> 6) * 32;  // 2048x2048
    int tx = thr & 31, ty = thr >> 5;
#pragma unroll
    for (int i = 0; i < 32; i += 8)
      tile[ty + i][tx] = Wo[(size_t)(r0 + ty + i) * 2048 + c0 + tx];
    __syncthreads();
#pragma unroll
    for (int i = 0; i < 32; i += 8)
      WoT[(size_t)(c0 + ty + i) * 2048 + r0 + tx] = __float2bfloat16(tile[tx][ty + i]);
  } else if (blk < P1_RT) {
    int tid = (blk - P1_WO) * 256 + thr;  // S*64
    int j = tid & 63, s = tid >> 6;
    int sec = (j < 8) ? 0 : (j < 16) ? 1 : (j < 40) ? 2 : 3;
    float pos = (float)pid[sec * SS + s];
    float inv = __expf(-(float)j * 0.14391156831212787f);  // ln(10000)/64
    float a = pos * inv;
    cosT[tid] = cosf(a);
    sinT[tid] = sinf(a);
  } else if (blk < P1_CK) {
    int tid = (blk - P1_RT) * 256 + thr;
    int d8 = tid & 15, l = (tid >> 4) & 2047, h = (tid >> 15) & 7, b = tid >> 18;
    const float* s = ck + (((size_t)b * CTXL + l) * NKV + h) * HD + d8 * 8;
    const float4* p = (const float4*)s;
    float4 a = p[0], bb = p[1];
    float f[8] = {a.x, a.y, a.z, a.w, bb.x, bb.y, bb.z, bb.w};
    store_bf8(Kf + (((size_t)(b * NKV + h)) * LT + l) * HD + d8 * 8, f);
  } else {
    int j = blk - P1_CK;
    int l0 = (j & 63) * 32, d0 = ((j >> 6) & 3) * 32;
    int bz = j >> 8, b = bz >> 3, h = bz & 7;
    int tx = thr & 31, ty = thr >> 5;
#pragma unroll
    for (int i = 0; i < 32; i += 8)
      tile[ty + i][tx] =
          cv[(((size_t)b * CTXL + l0 + ty + i) * NKV + h) * HD + d0 + tx];
    __syncthreads();
#pragma unroll
    for (int i = 0; i < 32; i += 8)
      Vt[(((size_t)(b * NKV + h)) * HD + d0 + ty + i) * LT + l0 + tx] =
          __float2bfloat16(tile[tx][ty + i]);
  }
}

// ---------------- prep2: rope_k + vt_from_qkv (both read qkv) --------------
__global__ void prep2(const bf16* __restrict__ qkv, const float* __restrict__ cosT,
                      const float* __restrict__ sinT, bf16* __restrict__ Kf,
                      bf16* __restrict__ Vt) {
  __shared__ float tile[32][33];
  const int blk = blockIdx.x, thr = threadIdx.x;
  if (blk < 8192) {
    int tid = blk * 256 + thr;
    int j = tid & 63, h = (tid >> 6) & 7, s = (tid >> 9) & 1023, b = tid >> 19;
    const bf16* src = qkv + ((size_t)b * SS + s) * QKVN + 2048 + h * HD;
    float x1 = __bfloat162float(src[j]), x2 = __bfloat162float(src[j + 64]);
    float c = cosT[s * 64 + j], sn = sinT[s * 64 + j];
    bf16* dst = Kf + (((size_t)(b * NKV + h)) * LT + CTXL + s) * HD;
    dst[j] = __float2bfloat16(x1 * c - x2 * sn);
    dst[j + 64] = __float2bfloat16(x2 * c + x1 * sn);
  } else {
    int j = blk - 8192;
    int s0 = (j & 31) * 32, d0 = ((j >> 5) & 3) * 32;
    int bz = j >> 7, b = bz >> 3, h = bz & 7;
    int tx = thr & 31, ty = thr >> 5;
#pragma unroll
    for (int i = 0; i < 32; i += 8)
      tile[ty + i][tx] = __bfloat162float(
          qkv[((size_t)b * SS + s0 + ty + i) * QKVN + 3072 + h * HD + d0 + tx]);
    __syncthreads();
#pragma unroll
    for (int i = 0; i < 32; i += 8)
      Vt[(((size_t)(b * NKV + h)) * HD + d0 + ty + i) * LT + CTXL + s0 + tx] =
          __float2bfloat16(tile[tx][ty + i]);
  }
}

// ---------------- GEMM: C[M][N] = A[M][K] * BT[N][K]^T ----------------
template <typename OT>
__global__ __launch_bounds__(512, 1) void gemm_bt(const bf16* __restrict__ A,
                                                  const bf16* __restrict__ BT,
                                                  OT* __restrict__ C, int M, int N,
                                                  int K) {
  __shared__ __attribute__((aligned(16))) bf16 lA[3][256][64];  // 96 KB
  __shared__ __attribute__((aligned(16))) bf16 lB[3][128][64];  // 48 KB
  const int t = threadIdx.x;
  const int lane = t & 63, w = t >> 6;
  const int wr = w >> 1, wc = w & 1;
  const int lrow = lane & 15, kgrp = lane >> 4;
  const int rchk = lrow & 7;
  const int lin = blockIdx.y * gridDim.x + blockIdx.x;
  const int qq = (gridDim.x * gridDim.y) >> 3;
  const int swz = (lin & 7) * qq + (lin >> 3);
  const int bx = swz % gridDim.x, by = swz / gridDim.x;
  const int m0 = by * 256, n0 = bx * 128;
  const int srow = lane >> 3;
  const int schk = (lane & 7) ^ srow;
  const f32x4 fz = {0.f, 0.f, 0.f, 0.f};
  f32x4 acc[4][4];
#pragma unroll
  for (int i = 0; i < 4; ++i)
#pragma unroll
    for (int j = 0; j < 4; ++j) acc[i][j] = fz;
  const int NTK = K >> 6;

#define GSTAGE(ib, kt)                                                      \
  do {                                                                      \
    _Pragma("unroll") for (int c = 0; c < 4; ++c) {                         \
      int ra = c * 64 + w * 8 + srow;                                       \
      gload_lds16(A + (size_t)(m0 + ra) * K + (kt)*64 + schk * 8,           \
                  &lA[ib][c * 64 + w * 8][0]);                              \
    }                                                                       \
    _Pragma("unroll") for (int c = 0; c < 2; ++c) {                         \
      int rb = c * 64 + w * 8 + srow;                                       \
      gload_lds16(BT + (size_t)(n0 + rb) * K + (kt)*64 + schk * 8,          \
                  &lB[ib][c * 64 + w * 8][0]);                              \
    }                                                                       \
  } while (0)

  GSTAGE(0, 0);
  GSTAGE(1, 1);
  int ib = 0;
  for (int kt = 0; kt < NTK; ++kt) {
    if (kt + 1 < NTK)
      asm volatile("s_waitcnt vmcnt(6) lgkmcnt(0)" ::: "memory");
    else
      asm volatile("s_waitcnt vmcnt(0) lgkmcnt(0)" ::: "memory");
    __builtin_amdgcn_s_barrier();
    __builtin_amdgcn_sched_barrier(0);
    if (kt + 2 < NTK) {
      int ib2 = ib + 2;
      if (ib2 >= 3) ib2 -= 3;
      GSTAGE(ib2, kt + 2);
    }
#pragma unroll
    for (int kk = 0; kk < 2; ++kk) {
      s16x8 af[4], bf[4];
#pragma unroll
      for (int i = 0; i < 4; ++i)
        af[i] = *(const s16x8*)&lA[ib][wr * 64 + i * 16 + lrow]
                                     [(((kk << 2) + kgrp) ^ rchk) * 8];
#pragma unroll
      for (int j = 0; j < 4; ++j)
        bf[j] = *(const s16x8*)&lB[ib][wc * 64 + j * 16 + lrow]
                                     [(((kk << 2) + kgrp) ^ rchk) * 8];
      __builtin_amdgcn_s_setprio(1);
#pragma unroll
      for (int i = 0; i < 4; ++i)
#pragma unroll
        for (int j = 0; j < 4; ++j) acc[i][j] = MFMA(af[i], bf[j], acc[i][j]);
      __builtin_amdgcn_s_setprio(0);
    }
    ++ib;
    if (ib >= 3) ib = 0;
  }
#undef GSTAGE

#pragma unroll
  for (int i = 0; i < 4; ++i)
#pragma unroll
    for (int j = 0; j < 4; ++j)
#pragma unroll
      for (int r = 0; r < 4; ++r) {
        int row = m0 + wr * 64 + i * 16 + kgrp * 4 + r;
        int col = n0 + wc * 64 + j * 16 + lrow;
        float v = acc[i][j][r];
        if constexpr (sizeof(OT) == 2)
          C[(size_t)row * N + col] = __float2bfloat16(v);
        else
          C[(size_t)row * N + col] = v;
      }
}

// ---------------- flash attention (KVBLK=128, K+V double-buffered) --------
// 256 q-rows/block, 8 waves x 32 rows. NEW vs R14: V double-buffered like K
// (V(t+1) staged during iter t, consumed from Vl[cur] a full iteration later)
// -> the mid-iteration V-DMA wait disappears; ONE barrier per iteration (24
// total, was 48). LDS: K 64K + V 64K + P 18K = 146 KB. P buffer is 16 rows
// per wave, row-frags f=0,1 processed sequentially through it (write f ->
// read pa[f] -> overwrite; same-wave DS ops are pipe-ordered, no barrier).
// XCD panel swizzle (R14, FETCH 205->35MB). Fused Q-RoPE prologue. Swapped
// QK^T, lane-local softmax, defer-max (T13).
// XOR chunk swizzle both sides (rule 21): K/V chunk^(row&15).

#define PSTR 72  // P row stride in elements: 144B = 16B-aligned
#define KVB 128
#define NTT 24   // LT / 128
#define SCALE2 0.1275174335919605f  // scale * log2(e)

__global__ __launch_bounds__(512, 2) void flash_attn(
    const bf16* __restrict__ qkv, const float* __restrict__ cosT,
    const float* __restrict__ sinT, const bf16* __restrict__ Kf,
    const bf16* __restrict__ Vt, bf16* __restrict__ O) {
  __shared__ __attribute__((aligned(16))) bf16 Kl[2][128][128];     // 64 KB
  __shared__ __attribute__((aligned(16))) bf16 Vl[2][128][128];     // 64 KB
  __shared__ __attribute__((aligned(16))) bf16 P_lds[8][16][PSTR];  // 18 KB
  const int t = threadIdx.x, lane = t & 63, w = t >> 6;
  // XCD panel swizzle (bijective): b=id>>6, hk=id&7, h=(hk<<1)|bit5, qb=bits3-4
  const int id = blockIdx.x;
  const int b = id >> 6, hk = id & 7;
  const int h = (hk << 1) | ((id >> 5) & 1);
  const int qb = (id >> 3) & 3;
  const int lrow = lane & 15, kgrp = lane >> 4;
  const bf16* Kp = Kf + (size_t)(b * NKV + hk) * LT * HD;
  const bf16* Vp = Vt + (size_t)(b * NKV + hk) * HD * LT;

  // prologue: load Q rows from qkv and apply RoPE in-register
  s16x8 qf[2][4];
#pragma unroll
  for (int f = 0; f < 2; ++f) {
    int srw_i = qb * 256 + w * 32 + f * 16 + lrow;
    const bf16* qrow = qkv + ((size_t)b * SS + srw_i) * QKVN + h * HD;
    s16x8 qr[4];
#pragma unroll
    for (int kd = 0; kd < 4; ++kd)
      qr[kd] = *(const s16x8*)&qrow[kd * 32 + kgrp * 8];
    const float* crow = cosT + srw_i * 64 + kgrp * 8;
    const float* srow = sinT + srw_i * 64 + kgrp * 8;
    float qv[4][8], cc[2][8], ssv[2][8];
#pragma unroll
    for (int kd = 0; kd < 4; ++kd)
#pragma unroll
      for (int j = 0; j < 8; ++j) qv[kd][j] = bf2f(qr[kd][j]);
#pragma unroll
    for (int g = 0; g < 2; ++g)
#pragma unroll
      for (int j = 0; j < 8; ++j) {
        cc[g][j] = crow[g * 32 + j];
        ssv[g][j] = srow[g * 32 + j];
      }
    bf16 o[4][8];
#pragma unroll
    for (int j = 0; j < 8; ++j) {
      o[0][j] = __float2bfloat16(qv[0][j] * cc[0][j] - qv[2][j] * ssv[0][j]);
      o[1][j] = __float2bfloat16(qv[1][j] * cc[1][j] - qv[3][j] * ssv[1][j]);
      o[2][j] = __float2bfloat16(qv[2][j] * cc[0][j] + qv[0][j] * ssv[0][j]);
      o[3][j] = __float2bfloat16(qv[3][j] * cc[1][j] + qv[1][j] * ssv[1][j]);
    }
#pragma unroll
    for (int kd = 0; kd < 4; ++kd) __builtin_memcpy(&qf[f][kd], o[kd], 16);
  }

  const f32x4 fz = {0.f, 0.f, 0.f, 0.f};
  f32x4 acc[2][8];
#pragma unroll
  for (int f = 0; f < 2; ++f)
#pragma unroll
    for (int i = 0; i < 8; ++i) acc[f][i] = fz;
  float m_[2] = {-1e30f, -1e30f}, l_[2] = {0.f, 0.f};

  // staging (8 waves, 512 threads, 4 loads/thread per K and V tile)
#define STAGE_K(buf, l0)                                                        \
  do {                                                                          \
    _Pragma("unroll") for (int c = 0; c < 4; ++c) {                             \
      int row = w * 16 + c * 4 + (lane >> 4);                                   \
      gload_lds16(Kp + (size_t)((l0) + row) * HD + ((lane & 15) ^ (row & 15)) * 8, \
                  &Kl[buf][w * 16 + c * 4][0]);                                 \
    }                                                                           \
  } while (0)
#define STAGE_V(buf, l0)                                                        \
  do {                                                                          \
    _Pragma("unroll") for (int c = 0; c < 4; ++c) {                             \
      int d = w * 16 + c * 4 + (lane >> 4);                                     \
      gload_lds16(Vp + (size_t)d * LT + (l0) + ((lane & 15) ^ (d & 15)) * 8,    \
                  &Vl[buf][w * 16 + c * 4][0]);                                 \
    }                                                                           \
  } while (0)

  STAGE_K(0, 0);
  STAGE_V(0, 0);
  __syncthreads();

  for (int tt = 0; tt < NTT; ++tt) {
    const int cur = tt & 1;
    if (tt + 1 < NTT) {
      STAGE_K(cur ^ 1, (tt + 1) * KVB);
      STAGE_V(cur ^ 1, (tt + 1) * KVB);
    }

    // QK^T swapped: sc[f][cf][r] = score for q-row (lane&15) of frag f,
    // kv = cf*16 + kgrp*4 + r  (cf 0..7 over 128 kv)
    f32x4 sc[2][8];
#pragma unroll
    for (int f = 0; f < 2; ++f)
#pragma unroll
      for (int cf = 0; cf < 8; ++cf) sc[f][cf] = fz;
#pragma unroll
    for (int cf = 0; cf < 8; ++cf)
#pragma unroll
      for (int kd = 0; kd < 4; ++kd) {
        s16x8 kb =
            *(const s16x8*)&Kl[cur][cf * 16 + lrow][((kd * 4 + kgrp) ^ lrow) * 8];
#pragma unroll
        for (int f = 0; f < 2; ++f) sc[f][cf] = MFMA(kb, qf[f][kd], sc[f][cf]);
      }

    // lane-local max over 32 scores, then 2 wide shfls
    float mxv[2];
#pragma unroll
    for (int f = 0; f < 2; ++f) {
      float mx = sc[f][0][0];
#pragma unroll
      for (int cf = 0; cf < 8; ++cf)
#pragma unroll
        for (int r = 0; r < 4; ++r) mx = fmaxf(mx, sc[f][cf][r]);
      mx *= SCALE2;
      mx = fmaxf(mx, __shfl_xor(mx, 16, 64));
      mx = fmaxf(mx, __shfl_xor(mx, 32, 64));
      mxv[f] = mx;
    }
    bool nb = (mxv[0] > m_[0] + 8.f) || (mxv[1] > m_[1] + 8.f);
    if (__any(nb)) {
#pragma unroll
      for (int f = 0; f < 2; ++f) {
        float mn = fmaxf(m_[f], mxv[f]);
        float so = exp2f(m_[f] - mn);
        m_[f] = mn;
        l_[f] *= so;
        float sob[4];
#pragma unroll
        for (int r = 0; r < 4; ++r) sob[r] = __shfl(so, kgrp * 4 + r, 16);
#pragma unroll
        for (int nd = 0; nd < 8; ++nd)
#pragma unroll
          for (int r = 0; r < 4; ++r) acc[f][nd][r] *= sob[r];
      }
    }

    // two kv-halves; within each, row-frags f=0,1 sequentially share the
    // 16-row P buffer (same-wave DS ops are pipe-ordered)
    float lp[2] = {0.f, 0.f};
#pragma unroll
    for (int half = 0; half < 2; ++half) {
      s16x8 pa[2][2];
#pragma unroll
      for (int f = 0; f < 2; ++f) {
#pragma unroll
        for (int cf = 0; cf < 4; ++cf) {
          int cfs = half * 4 + cf;
          bf16 pk[4];
#pragma unroll
          for (int r = 0; r < 4; ++r) {
            float p = exp2f(sc[f][cfs][r] * SCALE2 - m_[f]);
            lp[f] += p;
            pk[r] = __float2bfloat16(p);
          }
          __builtin_memcpy((void*)&P_lds[w][lrow][cf * 16 + kgrp * 4], pk, 8);
        }
#pragma unroll
        for (int kc = 0; kc < 2; ++kc)
          pa[f][kc] = *(const s16x8*)&P_lds[w][lrow][kc * 32 + kgrp * 8];
      }
#pragma unroll
      for (int nd = 0; nd < 8; ++nd)
#pragma unroll
        for (int kc = 0; kc < 2; ++kc) {
          s16x8 vb = *(const s16x8*)&Vl[cur][nd * 16 + lrow]
                                       [((half * 8 + kc * 4 + kgrp) ^ lrow) * 8];
#pragma unroll
          for (int f = 0; f < 2; ++f) acc[f][nd] = MFMA(pa[f][kc], vb, acc[f][nd]);
        }
    }
#pragma unroll
    for (int f = 0; f < 2; ++f) l_[f] += lp[f];

    __syncthreads();  // drains K/V(t+1) DMA; protects cur bufs for next stage
  }
#undef STAGE_K
#undef STAGE_V

  float li[2][4];
#pragma unroll
  for (int f = 0; f < 2; ++f) {
    float lv = l_[f];
    lv += __shfl_xor(lv, 16, 64);
    lv += __shfl_xor(lv, 32, 64);
#pragma unroll
    for (int r = 0; r < 4; ++r) li[f][r] = 1.f / __shfl(lv, kgrp * 4 + r, 16);
  }
#pragma unroll
  for (int f = 0; f < 2; ++f)
#pragma unroll
    for (int nd = 0; nd < 8; ++nd)
#pragma unroll
      for (int r = 0; r < 4; ++r) {
        int row = qb * 256 + w * 32 + f * 16 + kgrp * 4 + r;
        O[((size_t)b * SS + row) * 2048 + h * HD + nd * 16 + lrow] =
            __float2bfloat16(acc[f][nd][r] * li[f][r]);
      }
}

// ---------------- launch ----------------

extern "C" void kernel_launch(void* const* d_in, const int* in_sizes, int n_in,
                              void* d_out, int out_size, void* d_ws, size_t ws_size,
                              hipStream_t stream) {
  const float* hs = (const float*)d_in[0];
  const float* Wqkv = (const float*)d_in[1];
  const float* Wo = (const float*)d_in[2];
  const float* ctx_k = (const float*)d_in[3];
  const float* ctx_v = (const float*)d_in[4];
  const int* pid = (const int*)d_in[5];
  float* out = (float*)d_out;
  char* ws = (char*)d_ws;

  bf16* Hb = (bf16*)(ws);                      // 16.78 MB (reused as attn_out)
  bf16* WqT = (bf16*)(ws + 16777216);          // 16.78 MB
  bf16* WoT = (bf16*)(ws + 33554432);          // 8.39 MB
  bf16* qkv = (bf16*)(ws + 41943040);          // 33.55 MB
  bf16* Kfull = (bf16*)(ws + 92274688);        // 25.17 MB
  bf16* Vt = (bf16*)(ws + 117440512);          // 25.17 MB
  float* cosT = (float*)(ws + 142606336);      // 256 KB
  float* sinT = (float*)(ws + 142606336 + 262144);
  bf16* attn = Hb;  // alias: Hb dead after QKV GEMM

  prep1<<<P1_CV, 256, 0, stream>>>(hs, Wqkv, Wo, ctx_k, ctx_v, pid, Hb, WqT, WoT,
                                   Kfull, Vt, cosT, sinT);
  gemm_bt<bf16><<<dim3(QKVN / 128, MROWS / 256), 512, 0, stream>>>(
      Hb, WqT, qkv, MROWS, QKVN, HID);
  prep2<<<12288, 256, 0, stream>>>(qkv, cosT, sinT, Kfull, Vt);
  flash_attn<<<256, 512, 0, stream>>>(qkv, cosT, sinT, Kfull, Vt, attn);
  gemm_bt<float><<<dim3(2048 / 128, MROWS / 256), 512, 0, stream>>>(
      attn, WoT, out, MROWS, 2048, HID);
}

// Round 16
// 302.029 us; speedup vs baseline: 1.1929x; 1.0518x over previous
//
#include <hip/hip_runtime.h>
#include <hip/hip_bf16.h>
#include <stdint.h>

#define NH 16
#define NKV 8
#define HD 128
#define BB 4
#define SS 1024
#define CTXL 2048
#define LT 3072
#define HID 2048
#define QKVN 4096
#define MROWS 4096

typedef __hip_bfloat16 bf16;
using f32x4 = __attribute__((ext_vector_type(4))) float;
using s16x8 = __attribute__((ext_vector_type(8))) short;

#define MFMA(a, b, c) __builtin_amdgcn_mfma_f32_16x16x32_bf16((a), (b), (c), 0, 0, 0)

__device__ __forceinline__ void gload_lds16(const void* g, void* l) {
  __builtin_amdgcn_global_load_lds((const __attribute__((address_space(1))) void*)g,
                                   (__attribute__((address_space(3))) void*)l, 16, 0, 0);
}

__device__ __forceinline__ void store_bf8(bf16* dst, const float* f) {
  bf16 tmp[8];
#pragma unroll
  for (int j = 0; j < 8; ++j) tmp[j] = __float2bfloat16(f[j]);
  __builtin_memcpy((void*)dst, (const void*)tmp, 16);
}

__device__ __forceinline__ float bf2f(short x) {
  unsigned int u = ((unsigned int)(unsigned short)x) << 16;
  float f;
  __builtin_memcpy(&f, &u, 4);
  return f;
}

// ---------------- prep1: cvt + weight transposes + rope table + ctx K/V ----
#define P1_CVT 4096
#define P1_WQ (P1_CVT + 8192)
#define P1_WO (P1_WQ + 4096)
#define P1_RT (P1_WO + 256)
#define P1_CK (P1_RT + 4096)
#define P1_CV (P1_CK + 8192)

__global__ void prep1(const float* __restrict__ hs, const float* __restrict__ Wqkv,
                      const float* __restrict__ Wo, const float* __restrict__ ck,
                      const float* __restrict__ cv, const int* __restrict__ pid,
                      bf16* __restrict__ Hb, bf16* __restrict__ WqT,
                      bf16* __restrict__ WoT, bf16* __restrict__ Kf,
                      bf16* __restrict__ Vt, float* __restrict__ cosT,
                      float* __restrict__ sinT) {
  __shared__ float tile[32][33];
  const int blk = blockIdx.x, thr = threadIdx.x;
  if (blk < P1_CVT) {
    size_t tid = (size_t)blk * 256 + thr;
    const float4* p = (const float4*)(hs + tid * 8);
    float4 a = p[0], b = p[1];
    float f[8] = {a.x, a.y, a.z, a.w, b.x, b.y, b.z, b.w};
    store_bf8(Hb + tid * 8, f);
  } else if (blk < P1_WQ) {
    int j = blk - P1_CVT;
    int c0 = (j & 127) * 32, r0 = (j >> 7) * 32;  // R=2048 C=4096
    int tx = thr & 31, ty = thr >> 5;
#pragma unroll
    for (int i = 0; i < 32; i += 8)
      tile[ty + i][tx] = Wqkv[(size_t)(r0 + ty + i) * QKVN + c0 + tx];
    __syncthreads();
#pragma unroll
    for (int i = 0; i < 32; i += 8)
      WqT[(size_t)(c0 + ty + i) * HID + r0 + tx] = __float2bfloat16(tile[tx][ty + i]);
  } else if (blk < P1_WO) {
    int j = blk - P1_WQ;
    int c0 = (j & 63) * 32, r0 = (j >> 6) * 32;  // 2048x2048
    int tx = thr & 31, ty = thr >> 5;
#pragma unroll
    for (int i = 0; i < 32; i += 8)
      tile[ty + i][tx] = Wo[(size_t)(r0 + ty + i) * 2048 + c0 + tx];
    __syncthreads();
#pragma unroll
    for (int i = 0; i < 32; i += 8)
      WoT[(size_t)(c0 + ty + i) * 2048 + r0 + tx] = __float2bfloat16(tile[tx][ty + i]);
  } else if (blk < P1_RT) {
    int tid = (blk - P1_WO) * 256 + thr;  // S*64
    int j = tid & 63, s = tid >> 6;
    int sec = (j < 8) ? 0 : (j < 16) ? 1 : (j < 40) ? 2 : 3;
    float pos = (float)pid[sec * SS + s];
    float inv = __expf(-(float)j * 0.14391156831212787f);  // ln(10000)/64
    float a = pos * inv;
    cosT[tid] = cosf(a);
    sinT[tid] = sinf(a);
  } else if (blk < P1_CK) {
    int tid = (blk - P1_RT) * 256 + thr;
    int d8 = tid & 15, l = (tid >> 4) & 2047, h = (tid >> 15) & 7, b = tid >> 18;
    const float* s = ck + (((size_t)b * CTXL + l) * NKV + h) * HD + d8 * 8;
    const float4* p = (const float4*)s;
    float4 a = p[0], bb = p[1];
    float f[8] = {a.x, a.y, a.z, a.w, bb.x, bb.y, bb.z, bb.w};
    store_bf8(Kf + (((size_t)(b * NKV + h)) * LT + l) * HD + d8 * 8, f);
  } else {
    int j = blk - P1_CK;
    int l0 = (j & 63) * 32, d0 = ((j >> 6) & 3) * 32;
    int bz = j >> 8, b = bz >> 3, h = bz & 7;
    int tx = thr & 31, ty = thr >> 5;
#pragma unroll
    for (int i = 0; i < 32; i += 8)
      tile[ty + i][tx] =
          cv[(((size_t)b * CTXL + l0 + ty + i) * NKV + h) * HD + d0 + tx];
    __syncthreads();
#pragma unroll
    for (int i = 0; i < 32; i += 8)
      Vt[(((size_t)(b * NKV + h)) * HD + d0 + ty + i) * LT + l0 + tx] =
          __float2bfloat16(tile[tx][ty + i]);
  }
}

// ---------------- QKV GEMM with fused K-RoPE / V-transpose epilogue --------
// Same 256x128 / BK=64 / 3-buffer / counted-vmcnt(6) structure as gemm_bt.
// N-tile nt = n0>>7: nt<16 -> Q head, write qkv as before. nt in [16,24) ->
// K head h=nt-16: stage f32 tile into dead LDS (stride 129, conflict-free),
// apply RoPE (pair d <-> d+64 spans wc halves -> via LDS), write Kfull tail.
// nt>=24 -> V head h=nt-24: stage, write transposed into Vt tail.
// K/V halves of qkv are never written (nothing reads them).

__global__ __launch_bounds__(512, 1) void gemm_qkv(
    const bf16* __restrict__ A, const bf16* __restrict__ BT,
    bf16* __restrict__ qkv, bf16* __restrict__ Kf, bf16* __restrict__ Vt,
    const float* __restrict__ cosT, const float* __restrict__ sinT) {
  __shared__ __attribute__((aligned(16))) char smem[147456];  // lA 96K + lB 48K
  bf16* lA = (bf16*)smem;                    // [3][256][64]
  bf16* lB = (bf16*)(smem + 98304);          // [3][128][64]
  const int K = HID, N = QKVN;
  const int t = threadIdx.x;
  const int lane = t & 63, w = t >> 6;
  const int wr = w >> 1, wc = w & 1;
  const int lrow = lane & 15, kgrp = lane >> 4;
  const int rchk = lrow & 7;
  const int lin = blockIdx.y * gridDim.x + blockIdx.x;
  const int qq = (gridDim.x * gridDim.y) >> 3;
  const int swz = (lin & 7) * qq + (lin >> 3);
  const int bx = swz % gridDim.x, by = swz / gridDim.x;
  const int m0 = by * 256, n0 = bx * 128;
  const int srow = lane >> 3;
  const int schk = (lane & 7) ^ srow;
  const f32x4 fz = {0.f, 0.f, 0.f, 0.f};
  f32x4 acc[4][4];
#pragma unroll
  for (int i = 0; i < 4; ++i)
#pragma unroll
    for (int j = 0; j < 4; ++j) acc[i][j] = fz;
  const int NTK = K >> 6;  // 32

#define GSTAGE(ib, kt)                                                      \
  do {                                                                      \
    _Pragma("unroll") for (int c = 0; c < 4; ++c) {                         \
      int ra = c * 64 + w * 8 + srow;                                       \
      gload_lds16(A + (size_t)(m0 + ra) * K + (kt)*64 + schk * 8,           \
                  &lA[((ib)*256 + c * 64 + w * 8) * 64]);                   \
    }                                                                       \
    _Pragma("unroll") for (int c = 0; c < 2; ++c) {                         \
      int rb = c * 64 + w * 8 + srow;                                       \
      gload_lds16(BT + (size_t)(n0 + rb) * K + (kt)*64 + schk * 8,          \
                  &lB[((ib)*128 + c * 64 + w * 8) * 64]);                   \
    }                                                                       \
  } while (0)

  GSTAGE(0, 0);
  GSTAGE(1, 1);
  int ib = 0;
  for (int kt = 0; kt < NTK; ++kt) {
    if (kt + 1 < NTK)
      asm volatile("s_waitcnt vmcnt(6) lgkmcnt(0)" ::: "memory");
    else
      asm volatile("s_waitcnt vmcnt(0) lgkmcnt(0)" ::: "memory");
    __builtin_amdgcn_s_barrier();
    __builtin_amdgcn_sched_barrier(0);
    if (kt + 2 < NTK) {
      int ib2 = ib + 2;
      if (ib2 >= 3) ib2 -= 3;
      GSTAGE(ib2, kt + 2);
    }
#pragma unroll
    for (int kk = 0; kk < 2; ++kk) {
      s16x8 af[4], bf[4];
#pragma unroll
      for (int i = 0; i < 4; ++i)
        af[i] = *(const s16x8*)&lA[((ib)*256 + wr * 64 + i * 16 + lrow) * 64 +
                                   (((kk << 2) + kgrp) ^ rchk) * 8];
#pragma unroll
      for (int j = 0; j < 4; ++j)
        bf[j] = *(const s16x8*)&lB[((ib)*128 + wc * 64 + j * 16 + lrow) * 64 +
                                   (((kk << 2) + kgrp) ^ rchk) * 8];
      __builtin_amdgcn_s_setprio(1);
#pragma unroll
      for (int i = 0; i < 4; ++i)
#pragma unroll
        for (int j = 0; j < 4; ++j) acc[i][j] = MFMA(af[i], bf[j], acc[i][j]);
      __builtin_amdgcn_s_setprio(0);
    }
    ++ib;
    if (ib >= 3) ib = 0;
  }
#undef GSTAGE

  const int nt = n0 >> 7;          // head-tile index
  const int b = m0 >> 10, s0 = m0 & 1023;
  if (nt < 16) {
    // Q tiles: plain write to qkv
#pragma unroll
    for (int i = 0; i < 4; ++i)
#pragma unroll
      for (int j = 0; j < 4; ++j)
#pragma unroll
        for (int r = 0; r < 4; ++r) {
          int row = m0 + wr * 64 + i * 16 + kgrp * 4 + r;
          int col = n0 + wc * 64 + j * 16 + lrow;
          qkv[(size_t)row * N + col] = __float2bfloat16(acc[i][j][r]);
        }
  } else {
    __syncthreads();  // all waves done reading lA/lB (lgkmcnt drained)
    float* stage = (float*)smem;  // [256][129] f32 = 132,096 B <= 147,456
#pragma unroll
    for (int i = 0; i < 4; ++i)
#pragma unroll
      for (int j = 0; j < 4; ++j)
#pragma unroll
        for (int r = 0; r < 4; ++r)
          stage[(wr * 64 + i * 16 + kgrp * 4 + r) * 129 + wc * 64 + j * 16 + lrow] =
              acc[i][j][r];
    __syncthreads();
    if (nt < 24) {
      // K head: RoPE + write Kfull tail rows
      const int h = nt - 16;
#pragma unroll 4
      for (int it = 0; it < 32; ++it) {
        int idx = it * 512 + t;
        int r = idx >> 6, j = idx & 63;
        float x1 = stage[r * 129 + j], x2 = stage[r * 129 + j + 64];
        int s = s0 + r;
        float c = cosT[s * 64 + j], sn = sinT[s * 64 + j];
        bf16* dst = Kf + ((size_t)(b * NKV + h) * LT + CTXL + s) * HD;
        dst[j] = __float2bfloat16(x1 * c - x2 * sn);
        dst[j + 64] = __float2bfloat16(x2 * c + x1 * sn);
      }
    } else {
      // V head: transposed write into Vt tail columns
      const int h = nt - 24;
#pragma unroll 4
      for (int it = 0; it < 64; ++it) {
        int idx = it * 512 + t;
        int soff = idx & 255, d = idx >> 8;
        float v = stage[soff * 129 + d];
        Vt[((size_t)(b * NKV + h) * HD + d) * LT + CTXL + s0 + soff] =
            __float2bfloat16(v);
      }
    }
  }
}

// ---------------- GEMM: C[M][N] = A[M][K] * BT[N][K]^T (out-proj) ---------
template <typename OT>
__global__ __launch_bounds__(512, 1) void gemm_bt(const bf16* __restrict__ A,
                                                  const bf16* __restrict__ BT,
                                                  OT* __restrict__ C, int M, int N,
                                                  int K) {
  __shared__ __attribute__((aligned(16))) bf16 lA[3][256][64];  // 96 KB
  __shared__ __attribute__((aligned(16))) bf16 lB[3][128][64];  // 48 KB
  const int t = threadIdx.x;
  const int lane = t & 63, w = t >> 6;
  const int wr = w >> 1, wc = w & 1;
  const int lrow = lane & 15, kgrp = lane >> 4;
  const int rchk = lrow & 7;
  const int lin = blockIdx.y * gridDim.x + blockIdx.x;
  const int qq = (gridDim.x * gridDim.y) >> 3;
  const int swz = (lin & 7) * qq + (lin >> 3);
  const int bx = swz % gridDim.x, by = swz / gridDim.x;
  const int m0 = by * 256, n0 = bx * 128;
  const int srow = lane >> 3;
  const int schk = (lane & 7) ^ srow;
  const f32x4 fz = {0.f, 0.f, 0.f, 0.f};
  f32x4 acc[4][4];
#pragma unroll
  for (int i = 0; i < 4; ++i)
#pragma unroll
    for (int j = 0; j < 4; ++j) acc[i][j] = fz;
  const int NTK = K >> 6;

#define GSTAGE(ib, kt)                                                      \
  do {                                                                      \
    _Pragma("unroll") for (int c = 0; c < 4; ++c) {                         \
      int ra = c * 64 + w * 8 + srow;                                       \
      gload_lds16(A + (size_t)(m0 + ra) * K + (kt)*64 + schk * 8,           \
                  &lA[ib][c * 64 + w * 8][0]);                              \
    }                                                                       \
    _Pragma("unroll") for (int c = 0; c < 2; ++c) {                         \
      int rb = c * 64 + w * 8 + srow;                                       \
      gload_lds16(BT + (size_t)(n0 + rb) * K + (kt)*64 + schk * 8,          \
                  &lB[ib][c * 64 + w * 8][0]);                              \
    }                                                                       \
  } while (0)

  GSTAGE(0, 0);
  GSTAGE(1, 1);
  int ib = 0;
  for (int kt = 0; kt < NTK; ++kt) {
    if (kt + 1 < NTK)
      asm volatile("s_waitcnt vmcnt(6) lgkmcnt(0)" ::: "memory");
    else
      asm volatile("s_waitcnt vmcnt(0) lgkmcnt(0)" ::: "memory");
    __builtin_amdgcn_s_barrier();
    __builtin_amdgcn_sched_barrier(0);
    if (kt + 2 < NTK) {
      int ib2 = ib + 2;
      if (ib2 >= 3) ib2 -= 3;
      GSTAGE(ib2, kt + 2);
    }
#pragma unroll
    for (int kk = 0; kk < 2; ++kk) {
      s16x8 af[4], bf[4];
#pragma unroll
      for (int i = 0; i < 4; ++i)
        af[i] = *(const s16x8*)&lA[ib][wr * 64 + i * 16 + lrow]
                                     [(((kk << 2) + kgrp) ^ rchk) * 8];
#pragma unroll
      for (int j = 0; j < 4; ++j)
        bf[j] = *(const s16x8*)&lB[ib][wc * 64 + j * 16 + lrow]
                                     [(((kk << 2) + kgrp) ^ rchk) * 8];
      __builtin_amdgcn_s_setprio(1);
#pragma unroll
      for (int i = 0; i < 4; ++i)
#pragma unroll
        for (int j = 0; j < 4; ++j) acc[i][j] = MFMA(af[i], bf[j], acc[i][j]);
      __builtin_amdgcn_s_setprio(0);
    }
    ++ib;
    if (ib >= 3) ib = 0;
  }
#undef GSTAGE

#pragma unroll
  for (int i = 0; i < 4; ++i)
#pragma unroll
    for (int j = 0; j < 4; ++j)
#pragma unroll
      for (int r = 0; r < 4; ++r) {
        int row = m0 + wr * 64 + i * 16 + kgrp * 4 + r;
        int col = n0 + wc * 64 + j * 16 + lrow;
        float v = acc[i][j][r];
        if constexpr (sizeof(OT) == 2)
          C[(size_t)row * N + col] = __float2bfloat16(v);
        else
          C[(size_t)row * N + col] = v;
      }
}

// ---------------- flash attention (KVBLK=128, K+V double-buffered) --------
#define PSTR 72  // P row stride in elements: 144B = 16B-aligned
#define KVB 128
#define NTT 24   // LT / 128
#define SCALE2 0.1275174335919605f  // scale * log2(e)

__global__ __launch_bounds__(512, 2) void flash_attn(
    const bf16* __restrict__ qkv, const float* __restrict__ cosT,
    const float* __restrict__ sinT, const bf16* __restrict__ Kf,
    const bf16* __restrict__ Vt, bf16* __restrict__ O) {
  __shared__ __attribute__((aligned(16))) bf16 Kl[2][128][128];     // 64 KB
  __shared__ __attribute__((aligned(16))) bf16 Vl[2][128][128];     // 64 KB
  __shared__ __attribute__((aligned(16))) bf16 P_lds[8][16][PSTR];  // 18 KB
  const int t = threadIdx.x, lane = t & 63, w = t >> 6;
  // XCD panel swizzle (bijective): b=id>>6, hk=id&7, h=(hk<<1)|bit5, qb=bits3-4
  const int id = blockIdx.x;
  const int b = id >> 6, hk = id & 7;
  const int h = (hk << 1) | ((id >> 5) & 1);
  const int qb = (id >> 3) & 3;
  const int lrow = lane & 15, kgrp = lane >> 4;
  const bf16* Kp = Kf + (size_t)(b * NKV + hk) * LT * HD;
  const bf16* Vp = Vt + (size_t)(b * NKV + hk) * HD * LT;

  // prologue: load Q rows from qkv and apply RoPE in-register
  s16x8 qf[2][4];
#pragma unroll
  for (int f = 0; f < 2; ++f) {
    int srw_i = qb * 256 + w * 32 + f * 16 + lrow;
    const bf16* qrow = qkv + ((size_t)b * SS + srw_i) * QKVN + h * HD;
    s16x8 qr[4];
#pragma unroll
    for (int kd = 0; kd < 4; ++kd)
      qr[kd] = *(const s16x8*)&qrow[kd * 32 + kgrp * 8];
    const float* crow = cosT + srw_i * 64 + kgrp * 8;
    const float* srow = sinT + srw_i * 64 + kgrp * 8;
    float qv[4][8], cc[2][8], ssv[2][8];
#pragma unroll
    for (int kd = 0; kd < 4; ++kd)
#pragma unroll
      for (int j = 0; j < 8; ++j) qv[kd][j] = bf2f(qr[kd][j]);
#pragma unroll
    for (int g = 0; g < 2; ++g)
#pragma unroll
      for (int j = 0; j < 8; ++j) {
        cc[g][j] = crow[g * 32 + j];
        ssv[g][j] = srow[g * 32 + j];
      }
    bf16 o[4][8];
#pragma unroll
    for (int j = 0; j < 8; ++j) {
      o[0][j] = __float2bfloat16(qv[0][j] * cc[0][j] - qv[2][j] * ssv[0][j]);
      o[1][j] = __float2bfloat16(qv[1][j] * cc[1][j] - qv[3][j] * ssv[1][j]);
      o[2][j] = __float2bfloat16(qv[2][j] * cc[0][j] + qv[0][j] * ssv[0][j]);
      o[3][j] = __float2bfloat16(qv[3][j] * cc[1][j] + qv[1][j] * ssv[1][j]);
    }
#pragma unroll
    for (int kd = 0; kd < 4; ++kd) __builtin_memcpy(&qf[f][kd], o[kd], 16);
  }

  const f32x4 fz = {0.f, 0.f, 0.f, 0.f};
  f32x4 acc[2][8];
#pragma unroll
  for (int f = 0; f < 2; ++f)
#pragma unroll
    for (int i = 0; i < 8; ++i) acc[f][i] = fz;
  float m_[2] = {-1e30f, -1e30f}, l_[2] = {0.f, 0.f};

#define STAGE_K(buf, l0)                                                        \
  do {                                                                          \
    _Pragma("unroll") for (int c = 0; c < 4; ++c) {                             \
      int row = w * 16 + c * 4 + (lane >> 4);                                   \
      gload_lds16(Kp + (size_t)((l0) + row) * HD + ((lane & 15) ^ (row & 15)) * 8, \
                  &Kl[buf][w * 16 + c * 4][0]);                                 \
    }                                                                           \
  } while (0)
#define STAGE_V(buf, l0)                                                        \
  do {                                                                          \
    _Pragma("unroll") for (int c = 0; c < 4; ++c) {                             \
      int d = w * 16 + c * 4 + (lane >> 4);                                     \
      gload_lds16(Vp + (size_t)d * LT + (l0) + ((lane & 15) ^ (d & 15)) * 8,    \
                  &Vl[buf][w * 16 + c * 4][0]);                                 \
    }                                                                           \
  } while (0)

  STAGE_K(0, 0);
  STAGE_V(0, 0);
  __syncthreads();

  for (int tt = 0; tt < NTT; ++tt) {
    const int cur = tt & 1;
    if (tt + 1 < NTT) {
      STAGE_K(cur ^ 1, (tt + 1) * KVB);
      STAGE_V(cur ^ 1, (tt + 1) * KVB);
    }

    f32x4 sc[2][8];
#pragma unroll
    for (int f = 0; f < 2; ++f)
#pragma unroll
      for (int cf = 0; cf < 8; ++cf) sc[f][cf] = fz;
#pragma unroll
    for (int cf = 0; cf < 8; ++cf)
#pragma unroll
      for (int kd = 0; kd < 4; ++kd) {
        s16x8 kb =
            *(const s16x8*)&Kl[cur][cf * 16 + lrow][((kd * 4 + kgrp) ^ lrow) * 8];
#pragma unroll
        for (int f = 0; f < 2; ++f) sc[f][cf] = MFMA(kb, qf[f][kd], sc[f][cf]);
      }

    float mxv[2];
#pragma unroll
    for (int f = 0; f < 2; ++f) {
      float mx = sc[f][0][0];
#pragma unroll
      for (int cf = 0; cf < 8; ++cf)
#pragma unroll
        for (int r = 0; r < 4; ++r) mx = fmaxf(mx, sc[f][cf][r]);
      mx *= SCALE2;
      mx = fmaxf(mx, __shfl_xor(mx, 16, 64));
      mx = fmaxf(mx, __shfl_xor(mx, 32, 64));
      mxv[f] = mx;
    }
    bool nb = (mxv[0] > m_[0] + 8.f) || (mxv[1] > m_[1] + 8.f);
    if (__any(nb)) {
#pragma unroll
      for (int f = 0; f < 2; ++f) {
        float mn = fmaxf(m_[f], mxv[f]);
        float so = exp2f(m_[f] - mn);
        m_[f] = mn;
        l_[f] *= so;
        float sob[4];
#pragma unroll
        for (int r = 0; r < 4; ++r) sob[r] = __shfl(so, kgrp * 4 + r, 16);
#pragma unroll
        for (int nd = 0; nd < 8; ++nd)
#pragma unroll
          for (int r = 0; r < 4; ++r) acc[f][nd][r] *= sob[r];
      }
    }

    float lp[2] = {0.f, 0.f};
#pragma unroll
    for (int half = 0; half < 2; ++half) {
      s16x8 pa[2][2];
#pragma unroll
      for (int f = 0; f < 2; ++f) {
#pragma unroll
        for (int cf = 0; cf < 4; ++cf) {
          int cfs = half * 4 + cf;
          bf16 pk[4];
#pragma unroll
          for (int r = 0; r < 4; ++r) {
            float p = exp2f(sc[f][cfs][r] * SCALE2 - m_[f]);
            lp[f] += p;
            pk[r] = __float2bfloat16(p);
          }
          __builtin_memcpy((void*)&P_lds[w][lrow][cf * 16 + kgrp * 4], pk, 8);
        }
#pragma unroll
        for (int kc = 0; kc < 2; ++kc)
          pa[f][kc] = *(const s16x8*)&P_lds[w][lrow][kc * 32 + kgrp * 8];
      }
#pragma unroll
      for (int nd = 0; nd < 8; ++nd)
#pragma unroll
        for (int kc = 0; kc < 2; ++kc) {
          s16x8 vb = *(const s16x8*)&Vl[cur][nd * 16 + lrow]
                                       [((half * 8 + kc * 4 + kgrp) ^ lrow) * 8];
#pragma unroll
          for (int f = 0; f < 2; ++f) acc[f][nd] = MFMA(pa[f][kc], vb, acc[f][nd]);
        }
    }
#pragma unroll
    for (int f = 0; f < 2; ++f) l_[f] += lp[f];

    __syncthreads();  // drains K/V(t+1) DMA; protects cur bufs for next stage
  }
#undef STAGE_K
#undef STAGE_V

  float li[2][4];
#pragma unroll
  for (int f = 0; f < 2; ++f) {
    float lv = l_[f];
    lv += __shfl_xor(lv, 16, 64);
    lv += __shfl_xor(lv, 32, 64);
#pragma unroll
    for (int r = 0; r < 4; ++r) li[f][r] = 1.f / __shfl(lv, kgrp * 4 + r, 16);
  }
#pragma unroll
  for (int f = 0; f < 2; ++f)
#pragma unroll
    for (int nd = 0; nd < 8; ++nd)
#pragma unroll
      for (int r = 0; r < 4; ++r) {
        int row = qb * 256 + w * 32 + f * 16 + kgrp * 4 + r;
        O[((size_t)b * SS + row) * 2048 + h * HD + nd * 16 + lrow] =
            __float2bfloat16(acc[f][nd][r] * li[f][r]);
      }
}

// ---------------- launch ----------------

extern "C" void kernel_launch(void* const* d_in, const int* in_sizes, int n_in,
                              void* d_out, int out_size, void* d_ws, size_t ws_size,
                              hipStream_t stream) {
  const float* hs = (const float*)d_in[0];
  const float* Wqkv = (const float*)d_in[1];
  const float* Wo = (const float*)d_in[2];
  const float* ctx_k = (const float*)d_in[3];
  const float* ctx_v = (const float*)d_in[4];
  const int* pid = (const int*)d_in[5];
  float* out = (float*)d_out;
  char* ws = (char*)d_ws;

  bf16* Hb = (bf16*)(ws);                      // 16.78 MB (reused as attn_out)
  bf16* WqT = (bf16*)(ws + 16777216);          // 16.78 MB
  bf16* WoT = (bf16*)(ws + 33554432);          // 8.39 MB
  bf16* qkv = (bf16*)(ws + 41943040);          // 33.55 MB (only Q half written)
  bf16* Kfull = (bf16*)(ws + 92274688);        // 25.17 MB
  bf16* Vt = (bf16*)(ws + 117440512);          // 25.17 MB
  float* cosT = (float*)(ws + 142606336);      // 256 KB
  float* sinT = (float*)(ws + 142606336 + 262144);
  bf16* attn = Hb;  // alias: Hb dead after QKV GEMM

  prep1<<<P1_CV, 256, 0, stream>>>(hs, Wqkv, Wo, ctx_k, ctx_v, pid, Hb, WqT, WoT,
                                   Kfull, Vt, cosT, sinT);
  gemm_qkv<<<dim3(QKVN / 128, MROWS / 256), 512, 0, stream>>>(
      Hb, WqT, qkv, Kfull, Vt, cosT, sinT);
  flash_attn<<<256, 512, 0, stream>>>(qkv, cosT, sinT, Kfull, Vt, attn);
  gemm_bt<float><<<dim3(2048 / 128, MROWS / 256), 512, 0, stream>>>(
      attn, WoT, out, MROWS, 2048, HID);
}

// Round 17
// 292.630 us; speedup vs baseline: 1.2312x; 1.0321x over previous
//
#include <hip/hip_runtime.h>
#include <hip/hip_bf16.h>
#include <stdint.h>

#define NH 16
#define NKV 8
#define HD 128
#define BB 4
#define SS 1024
#define CTXL 2048
#define LT 3072
#define HID 2048
#define QKVN 4096
#define MROWS 4096

typedef __hip_bfloat16 bf16;
using f32x4 = __attribute__((ext_vector_type(4))) float;
using s16x8 = __attribute__((ext_vector_type(8))) short;

#define MFMA(a, b, c) __builtin_amdgcn_mfma_f32_16x16x32_bf16((a), (b), (c), 0, 0, 0)

__device__ __forceinline__ void gload_lds16(const void* g, void* l) {
  __builtin_amdgcn_global_load_lds((const __attribute__((address_space(1))) void*)g,
                                   (__attribute__((address_space(3))) void*)l, 16, 0, 0);
}

__device__ __forceinline__ void store_bf8(bf16* dst, const float* f) {
  bf16 tmp[8];
#pragma unroll
  for (int j = 0; j < 8; ++j) tmp[j] = __float2bfloat16(f[j]);
  __builtin_memcpy((void*)dst, (const void*)tmp, 16);
}

__device__ __forceinline__ float bf2f(short x) {
  unsigned int u = ((unsigned int)(unsigned short)x) << 16;
  float f;
  __builtin_memcpy(&f, &u, 4);
  return f;
}

// ---------------- prep1: cvt + weight transposes + rope table + ctx K/V ----
#define P1_CVT 4096
#define P1_WQ (P1_CVT + 8192)
#define P1_WO (P1_WQ + 4096)
#define P1_RT (P1_WO + 256)
#define P1_CK (P1_RT + 4096)
#define P1_CV (P1_CK + 8192)

__global__ void prep1(const float* __restrict__ hs, const float* __restrict__ Wqkv,
                      const float* __restrict__ Wo, const float* __restrict__ ck,
                      const float* __restrict__ cv, const int* __restrict__ pid,
                      bf16* __restrict__ Hb, bf16* __restrict__ WqT,
                      bf16* __restrict__ WoT, bf16* __restrict__ Kf,
                      bf16* __restrict__ Vt, float* __restrict__ cosT,
                      float* __restrict__ sinT) {
  __shared__ float tile[32][33];
  const int blk = blockIdx.x, thr = threadIdx.x;
  if (blk < P1_CVT) {
    size_t tid = (size_t)blk * 256 + thr;
    const float4* p = (const float4*)(hs + tid * 8);
    float4 a = p[0], b = p[1];
    float f[8] = {a.x, a.y, a.z, a.w, b.x, b.y, b.z, b.w};
    store_bf8(Hb + tid * 8, f);
  } else if (blk < P1_WQ) {
    int j = blk - P1_CVT;
    int c0 = (j & 127) * 32, r0 = (j >> 7) * 32;  // R=2048 C=4096
    int tx = thr & 31, ty = thr >> 5;
#pragma unroll
    for (int i = 0; i < 32; i += 8)
      tile[ty + i][tx] = Wqkv[(size_t)(r0 + ty + i) * QKVN + c0 + tx];
    __syncthreads();
#pragma unroll
    for (int i = 0; i < 32; i += 8)
      WqT[(size_t)(c0 + ty + i) * HID + r0 + tx] = __float2bfloat16(tile[tx][ty + i]);
  } else if (blk < P1_WO) {
    int j = blk - P1_WQ;
    int c0 = (j & 63) * 32, r0 = (j >> 6) * 32;  // 2048x2048
    int tx = thr & 31, ty = thr >> 5;
#pragma unroll
    for (int i = 0; i < 32; i += 8)
      tile[ty + i][tx] = Wo[(size_t)(r0 + ty + i) * 2048 + c0 + tx];
    __syncthreads();
#pragma unroll
    for (int i = 0; i < 32; i += 8)
      WoT[(size_t)(c0 + ty + i) * 2048 + r0 + tx] = __float2bfloat16(tile[tx][ty + i]);
  } else if (blk < P1_RT) {
    int tid = (blk - P1_WO) * 256 + thr;  // S*64
    int j = tid & 63, s = tid >> 6;
    int sec = (j < 8) ? 0 : (j < 16) ? 1 : (j < 40) ? 2 : 3;
    float pos = (float)pid[sec * SS + s];
    float inv = __expf(-(float)j * 0.14391156831212787f);  // ln(10000)/64
    float a = pos * inv;
    cosT[tid] = cosf(a);
    sinT[tid] = sinf(a);
  } else if (blk < P1_CK) {
    int tid = (blk - P1_RT) * 256 + thr;
    int d8 = tid & 15, l = (tid >> 4) & 2047, h = (tid >> 15) & 7, b = tid >> 18;
    const float* s = ck + (((size_t)b * CTXL + l) * NKV + h) * HD + d8 * 8;
    const float4* p = (const float4*)s;
    float4 a = p[0], bb = p[1];
    float f[8] = {a.x, a.y, a.z, a.w, bb.x, bb.y, bb.z, bb.w};
    store_bf8(Kf + (((size_t)(b * NKV + h)) * LT + l) * HD + d8 * 8, f);
  } else {
    int j = blk - P1_CK;
    int l0 = (j & 63) * 32, d0 = ((j >> 6) & 3) * 32;
    int bz = j >> 8, b = bz >> 3, h = bz & 7;
    int tx = thr & 31, ty = thr >> 5;
#pragma unroll
    for (int i = 0; i < 32; i += 8)
      tile[ty + i][tx] =
          cv[(((size_t)b * CTXL + l0 + ty + i) * NKV + h) * HD + d0 + tx];
    __syncthreads();
#pragma unroll
    for (int i = 0; i < 32; i += 8)
      Vt[(((size_t)(b * NKV + h)) * HD + d0 + ty + i) * LT + l0 + tx] =
          __float2bfloat16(tile[tx][ty + i]);
  }
}

// ---------------- QKV GEMM: 256x256 tile, 4-phase/K-tile interleave --------
// BM=BN=256, BK=64, 8 waves (2M x 4N), acc[8][4]. Two 64KB LDS slots (one
// K-tile each, alternating). Per phase: stage 1 half-tile (2 DMA) ->
// vmcnt(2) (never 0; at the barrier all OLDER stages have landed chip-wide)
// -> barrier -> 12 ds_read_b128 (XOR chunk swizzle both sides, rule 21) ->
// lgkmcnt(0)+sched_barrier (rule 18) -> 16 MFMA (setprio) -> barrier.
// Stage order per tile: A0,B0,A1,B1; worst-case stage->consume distance is
// 1 phase (B1), certified by the consuming phase's own vmcnt(2)+barrier.
// Epilogue: Q tiles direct write; K/V tiles stage f32 per-head through
// [256][129] LDS (aliases dead buffers), RoPE / transpose out (2 heads).

__global__ __launch_bounds__(512, 1) void gemm_qkv(
    const bf16* __restrict__ A, const bf16* __restrict__ BT,
    bf16* __restrict__ qkv, bf16* __restrict__ Kf, bf16* __restrict__ Vt,
    const float* __restrict__ cosT, const float* __restrict__ sinT) {
  __shared__ __attribute__((aligned(16))) char smem[132096];
  bf16* lds = (bf16*)smem;
#define lAp(s, hf) (lds + ((s)*2 + (hf)) * 8192)
#define lBp(s, hf) (lds + 32768 + ((s)*2 + (hf)) * 8192)
  const int K = HID;
  const int t = threadIdx.x;
  const int lane = t & 63, w = t >> 6;
  const int wr = w >> 2, wc = w & 3;  // 2M x 4N
  const int lrow = lane & 15, kgrp = lane >> 4;
  const int lin = blockIdx.y * gridDim.x + blockIdx.x;
  const int qq = (gridDim.x * gridDim.y) >> 3;
  const int swz = (lin & 7) * qq + (lin >> 3);
  const int bx = swz % gridDim.x, by = swz / gridDim.x;
  const int m0 = by * 256, n0 = bx * 256;
  const f32x4 fz = {0.f, 0.f, 0.f, 0.f};
  f32x4 acc[8][4];
#pragma unroll
  for (int i = 0; i < 8; ++i)
#pragma unroll
    for (int j = 0; j < 4; ++j) acc[i][j] = fz;

#define STAGEH(sslot, skt, isB, shalf)                                        \
  do {                                                                        \
    _Pragma("unroll") for (int c = 0; c < 2; ++c) {                           \
      int row = w * 16 + c * 8 + (lane >> 3);                                 \
      int sch = (lane & 7) ^ (lane >> 3);                                     \
      const bf16* src =                                                       \
          (isB) ? (BT + (size_t)(n0 + (shalf)*128 + row) * K + (skt)*64 + sch * 8) \
                : (A + (size_t)(m0 + (shalf)*128 + row) * K + (skt)*64 + sch * 8); \
      bf16* dst = ((isB) ? lBp((sslot), (shalf)) : lAp((sslot), (shalf))) +   \
                  (w * 16 + c * 8) * 64;                                      \
      gload_lds16(src, dst);                                                  \
    }                                                                         \
  } while (0)

#define PHASE(cslot, qm, qn, DOST, sslot, skt, isB, shalf)                    \
  do {                                                                        \
    if (DOST) {                                                               \
      STAGEH(sslot, skt, isB, shalf);                                         \
      asm volatile("s_waitcnt vmcnt(2)" ::: "memory");                        \
    } else {                                                                  \
      asm volatile("s_waitcnt vmcnt(0)" ::: "memory");                        \
    }                                                                         \
    __builtin_amdgcn_s_barrier();                                             \
    __builtin_amdgcn_sched_barrier(0);                                        \
    s16x8 af_[4][2], bf_[2][2];                                               \
    _Pragma("unroll") for (int fi = 0; fi < 4; ++fi)                          \
        _Pragma("unroll") for (int ks = 0; ks < 2; ++ks) {                    \
      int row = (qm)*64 + fi * 16 + lrow;                                     \
      af_[fi][ks] = *(const s16x8*)&lAp(cslot, wr)[row * 64 +                 \
                                                   ((ks * 4 + kgrp) ^ (lrow & 7)) * 8]; \
    }                                                                         \
    _Pragma("unroll") for (int fj = 0; fj < 2; ++fj)                          \
        _Pragma("unroll") for (int ks = 0; ks < 2; ++ks) {                    \
      int col = (wc & 1) * 64 + (qn)*32 + fj * 16 + lrow;                     \
      bf_[fj][ks] = *(const s16x8*)&lBp(cslot, wc >> 1)[col * 64 +            \
                                                        ((ks * 4 + kgrp) ^ (lrow & 7)) * 8]; \
    }                                                                         \
    asm volatile("s_waitcnt lgkmcnt(0)" ::: "memory");                        \
    __builtin_amdgcn_sched_barrier(0);                                        \
    __builtin_amdgcn_s_setprio(1);                                            \
    _Pragma("unroll") for (int fi = 0; fi < 4; ++fi)                          \
        _Pragma("unroll") for (int fj = 0; fj < 2; ++fj)                      \
            _Pragma("unroll") for (int ks = 0; ks < 2; ++ks)                  \
                acc[(qm)*4 + fi][(qn)*2 + fj] =                               \
        MFMA(af_[fi][ks], bf_[fj][ks], acc[(qm)*4 + fi][(qn)*2 + fj]);        \
    __builtin_amdgcn_s_setprio(0);                                            \
    __builtin_amdgcn_s_barrier();                                             \
  } while (0)

  // prologue: tile 0 -> slot 0 (4 halves), full drain, barrier
  STAGEH(0, 0, 0, 0);
  STAGEH(0, 0, 1, 0);
  STAGEH(0, 0, 0, 1);
  STAGEH(0, 0, 1, 1);
  asm volatile("s_waitcnt vmcnt(0)" ::: "memory");
  __builtin_amdgcn_s_barrier();

  for (int kt = 0; kt < 32; kt += 2) {
    // tile kt (slot 0); stage tile kt+1 -> slot 1
    PHASE(0, 0, 0, true, 1, kt + 1, 0, 0);
    PHASE(0, 1, 0, true, 1, kt + 1, 1, 0);
    PHASE(0, 0, 1, true, 1, kt + 1, 0, 1);
    PHASE(0, 1, 1, true, 1, kt + 1, 1, 1);
    // tile kt+1 (slot 1); stage tile kt+2 -> slot 0 (if exists)
    const bool d2 = (kt + 2 < 32);
    PHASE(1, 0, 0, d2, 0, kt + 2, 0, 0);
    PHASE(1, 1, 0, d2, 0, kt + 2, 1, 0);
    PHASE(1, 0, 1, d2, 0, kt + 2, 0, 1);
    PHASE(1, 1, 1, d2, 0, kt + 2, 1, 1);
  }
#undef PHASE
#undef STAGEH

  const int b = m0 >> 10, s0 = m0 & 1023;
  if (n0 < 2048) {
    // Q tiles: direct write
#pragma unroll
    for (int fm = 0; fm < 8; ++fm)
#pragma unroll
      for (int fn = 0; fn < 4; ++fn)
#pragma unroll
        for (int r = 0; r < 4; ++r) {
          int row = m0 + wr * 128 + fm * 16 + kgrp * 4 + r;
          int col = n0 + wc * 64 + fn * 16 + lrow;
          qkv[(size_t)row * QKVN + col] = __float2bfloat16(acc[fm][fn][r]);
        }
  } else {
    float* stage = (float*)smem;  // [256][129] f32 = 132096 B
#pragma unroll 1
    for (int hh = 0; hh < 2; ++hh) {
      __syncthreads();
      if ((wc >> 1) == hh) {
#pragma unroll
        for (int fm = 0; fm < 8; ++fm)
#pragma unroll
          for (int fn = 0; fn < 4; ++fn)
#pragma unroll
            for (int r = 0; r < 4; ++r) {
              int rr = wr * 128 + fm * 16 + kgrp * 4 + r;
              int cc = (wc & 1) * 64 + fn * 16 + lrow;
              stage[rr * 129 + cc] = acc[fm][fn][r];
            }
      }
      __syncthreads();
      if (n0 < 3072) {
        int h = ((n0 - 2048) >> 7) + hh;
#pragma unroll 4
        for (int it = 0; it < 32; ++it) {
          int idx = it * 512 + t;
          int r = idx >> 6, j = idx & 63;
          float x1 = stage[r * 129 + j], x2 = stage[r * 129 + j + 64];
          int s = s0 + r;
          float c = cosT[s * 64 + j], sn = sinT[s * 64 + j];
          bf16* dst = Kf + ((size_t)(b * NKV + h) * LT + CTXL + s) * HD;
          dst[j] = __float2bfloat16(x1 * c - x2 * sn);
          dst[j + 64] = __float2bfloat16(x2 * c + x1 * sn);
        }
      } else {
        int h = ((n0 - 3072) >> 7) + hh;
#pragma unroll 4
        for (int it = 0; it < 64; ++it) {
          int idx = it * 512 + t;
          int soff = idx & 255, d = idx >> 8;
          Vt[((size_t)(b * NKV + h) * HD + d) * LT + CTXL + s0 + soff] =
              __float2bfloat16(stage[soff * 129 + d]);
        }
      }
    }
  }
#undef lAp
#undef lBp
}

// ---------------- GEMM: C[M][N] = A[M][K] * BT[N][K]^T (out-proj) ---------
template <typename OT>
__global__ __launch_bounds__(512, 1) void gemm_bt(const bf16* __restrict__ A,
                                                  const bf16* __restrict__ BT,
                                                  OT* __restrict__ C, int M, int N,
                                                  int K) {
  __shared__ __attribute__((aligned(16))) bf16 lA[3][256][64];  // 96 KB
  __shared__ __attribute__((aligned(16))) bf16 lB[3][128][64];  // 48 KB
  const int t = threadIdx.x;
  const int lane = t & 63, w = t >> 6;
  const int wr = w >> 1, wc = w & 1;
  const int lrow = lane & 15, kgrp = lane >> 4;
  const int rchk = lrow & 7;
  const int lin = blockIdx.y * gridDim.x + blockIdx.x;
  const int qq = (gridDim.x * gridDim.y) >> 3;
  const int swz = (lin & 7) * qq + (lin >> 3);
  const int bx = swz % gridDim.x, by = swz / gridDim.x;
  const int m0 = by * 256, n0 = bx * 128;
  const int srow = lane >> 3;
  const int schk = (lane & 7) ^ srow;
  const f32x4 fz = {0.f, 0.f, 0.f, 0.f};
  f32x4 acc[4][4];
#pragma unroll
  for (int i = 0; i < 4; ++i)
#pragma unroll
    for (int j = 0; j < 4; ++j) acc[i][j] = fz;
  const int NTK = K >> 6;

#define GSTAGE(ib, kt)                                                      \
  do {                                                                      \
    _Pragma("unroll") for (int c = 0; c < 4; ++c) {                         \
      int ra = c * 64 + w * 8 + srow;                                       \
      gload_lds16(A + (size_t)(m0 + ra) * K + (kt)*64 + schk * 8,           \
                  &lA[ib][c * 64 + w * 8][0]);                              \
    }                                                                       \
    _Pragma("unroll") for (int c = 0; c < 2; ++c) {                         \
      int rb = c * 64 + w * 8 + srow;                                       \
      gload_lds16(BT + (size_t)(n0 + rb) * K + (kt)*64 + schk * 8,          \
                  &lB[ib][c * 64 + w * 8][0]);                              \
    }                                                                       \
  } while (0)

  GSTAGE(0, 0);
  GSTAGE(1, 1);
  int ib = 0;
  for (int kt = 0; kt < NTK; ++kt) {
    if (kt + 1 < NTK)
      asm volatile("s_waitcnt vmcnt(6) lgkmcnt(0)" ::: "memory");
    else
      asm volatile("s_waitcnt vmcnt(0) lgkmcnt(0)" ::: "memory");
    __builtin_amdgcn_s_barrier();
    __builtin_amdgcn_sched_barrier(0);
    if (kt + 2 < NTK) {
      int ib2 = ib + 2;
      if (ib2 >= 3) ib2 -= 3;
      GSTAGE(ib2, kt + 2);
    }
#pragma unroll
    for (int kk = 0; kk < 2; ++kk) {
      s16x8 af[4], bf[4];
#pragma unroll
      for (int i = 0; i < 4; ++i)
        af[i] = *(const s16x8*)&lA[ib][wr * 64 + i * 16 + lrow]
                                     [(((kk << 2) + kgrp) ^ rchk) * 8];
#pragma unroll
      for (int j = 0; j < 4; ++j)
        bf[j] = *(const s16x8*)&lB[ib][wc * 64 + j * 16 + lrow]
                                     [(((kk << 2) + kgrp) ^ rchk) * 8];
      __builtin_amdgcn_s_setprio(1);
#pragma unroll
      for (int i = 0; i < 4; ++i)
#pragma unroll
        for (int j = 0; j < 4; ++j) acc[i][j] = MFMA(af[i], bf[j], acc[i][j]);
      __builtin_amdgcn_s_setprio(0);
    }
    ++ib;
    if (ib >= 3) ib = 0;
  }
#undef GSTAGE

#pragma unroll
  for (int i = 0; i < 4; ++i)
#pragma unroll
    for (int j = 0; j < 4; ++j)
#pragma unroll
      for (int r = 0; r < 4; ++r) {
        int row = m0 + wr * 64 + i * 16 + kgrp * 4 + r;
        int col = n0 + wc * 64 + j * 16 + lrow;
        float v = acc[i][j][r];
        if constexpr (sizeof(OT) == 2)
          C[(size_t)row * N + col] = __float2bfloat16(v);
        else
          C[(size_t)row * N + col] = v;
      }
}

// ---------------- flash attention (KVBLK=128, K+V double-buffered) --------
#define PSTR 72  // P row stride in elements: 144B = 16B-aligned
#define KVB 128
#define NTT 24   // LT / 128
#define SCALE2 0.1275174335919605f  // scale * log2(e)

__global__ __launch_bounds__(512, 2) void flash_attn(
    const bf16* __restrict__ qkv, const float* __restrict__ cosT,
    const float* __restrict__ sinT, const bf16* __restrict__ Kf,
    const bf16* __restrict__ Vt, bf16* __restrict__ O) {
  __shared__ __attribute__((aligned(16))) bf16 Kl[2][128][128];     // 64 KB
  __shared__ __attribute__((aligned(16))) bf16 Vl[2][128][128];     // 64 KB
  __shared__ __attribute__((aligned(16))) bf16 P_lds[8][16][PSTR];  // 18 KB
  const int t = threadIdx.x, lane = t & 63, w = t >> 6;
  // XCD panel swizzle (bijective): b=id>>6, hk=id&7, h=(hk<<1)|bit5, qb=bits3-4
  const int id = blockIdx.x;
  const int b = id >> 6, hk = id & 7;
  const int h = (hk << 1) | ((id >> 5) & 1);
  const int qb = (id >> 3) & 3;
  const int lrow = lane & 15, kgrp = lane >> 4;
  const bf16* Kp = Kf + (size_t)(b * NKV + hk) * LT * HD;
  const bf16* Vp = Vt + (size_t)(b * NKV + hk) * HD * LT;

  // prologue: load Q rows from qkv and apply RoPE in-register
  s16x8 qf[2][4];
#pragma unroll
  for (int f = 0; f < 2; ++f) {
    int srw_i = qb * 256 + w * 32 + f * 16 + lrow;
    const bf16* qrow = qkv + ((size_t)b * SS + srw_i) * QKVN + h * HD;
    s16x8 qr[4];
#pragma unroll
    for (int kd = 0; kd < 4; ++kd)
      qr[kd] = *(const s16x8*)&qrow[kd * 32 + kgrp * 8];
    const float* crow = cosT + srw_i * 64 + kgrp * 8;
    const float* srow = sinT + srw_i * 64 + kgrp * 8;
    float qv[4][8], cc[2][8], ssv[2][8];
#pragma unroll
    for (int kd = 0; kd < 4; ++kd)
#pragma unroll
      for (int j = 0; j < 8; ++j) qv[kd][j] = bf2f(qr[kd][j]);
#pragma unroll
    for (int g = 0; g < 2; ++g)
#pragma unroll
      for (int j = 0; j < 8; ++j) {
        cc[g][j] = crow[g * 32 + j];
        ssv[g][j] = srow[g * 32 + j];
      }
    bf16 o[4][8];
#pragma unroll
    for (int j = 0; j < 8; ++j) {
      o[0][j] = __float2bfloat16(qv[0][j] * cc[0][j] - qv[2][j] * ssv[0][j]);
      o[1][j] = __float2bfloat16(qv[1][j] * cc[1][j] - qv[3][j] * ssv[1][j]);
      o[2][j] = __float2bfloat16(qv[2][j] * cc[0][j] + qv[0][j] * ssv[0][j]);
      o[3][j] = __float2bfloat16(qv[3][j] * cc[1][j] + qv[1][j] * ssv[1][j]);
    }
#pragma unroll
    for (int kd = 0; kd < 4; ++kd) __builtin_memcpy(&qf[f][kd], o[kd], 16);
  }

  const f32x4 fz = {0.f, 0.f, 0.f, 0.f};
  f32x4 acc[2][8];
#pragma unroll
  for (int f = 0; f < 2; ++f)
#pragma unroll
    for (int i = 0; i < 8; ++i) acc[f][i] = fz;
  float m_[2] = {-1e30f, -1e30f}, l_[2] = {0.f, 0.f};

#define STAGE_K(buf, l0)                                                        \
  do {                                                                          \
    _Pragma("unroll") for (int c = 0; c < 4; ++c) {                             \
      int row = w * 16 + c * 4 + (lane >> 4);                                   \
      gload_lds16(Kp + (size_t)((l0) + row) * HD + ((lane & 15) ^ (row & 15)) * 8, \
                  &Kl[buf][w * 16 + c * 4][0]);                                 \
    }                                                                           \
  } while (0)
#define STAGE_V(buf, l0)                                                        \
  do {                                                                          \
    _Pragma("unroll") for (int c = 0; c < 4; ++c) {                             \
      int d = w * 16 + c * 4 + (lane >> 4);                                     \
      gload_lds16(Vp + (size_t)d * LT + (l0) + ((lane & 15) ^ (d & 15)) * 8,    \
                  &Vl[buf][w * 16 + c * 4][0]);                                 \
    }                                                                           \
  } while (0)

  STAGE_K(0, 0);
  STAGE_V(0, 0);
  __syncthreads();

  for (int tt = 0; tt < NTT; ++tt) {
    const int cur = tt & 1;
    if (tt + 1 < NTT) {
      STAGE_K(cur ^ 1, (tt + 1) * KVB);
      STAGE_V(cur ^ 1, (tt + 1) * KVB);
    }

    f32x4 sc[2][8];
#pragma unroll
    for (int f = 0; f < 2; ++f)
#pragma unroll
      for (int cf = 0; cf < 8; ++cf) sc[f][cf] = fz;
#pragma unroll
    for (int cf = 0; cf < 8; ++cf)
#pragma unroll
      for (int kd = 0; kd < 4; ++kd) {
        s16x8 kb =
            *(const s16x8*)&Kl[cur][cf * 16 + lrow][((kd * 4 + kgrp) ^ lrow) * 8];
#pragma unroll
        for (int f = 0; f < 2; ++f) sc[f][cf] = MFMA(kb, qf[f][kd], sc[f][cf]);
      }

    float mxv[2];
#pragma unroll
    for (int f = 0; f < 2; ++f) {
      float mx = sc[f][0][0];
#pragma unroll
      for (int cf = 0; cf < 8; ++cf)
#pragma unroll
        for (int r = 0; r < 4; ++r) mx = fmaxf(mx, sc[f][cf][r]);
      mx *= SCALE2;
      mx = fmaxf(mx, __shfl_xor(mx, 16, 64));
      mx = fmaxf(mx, __shfl_xor(mx, 32, 64));
      mxv[f] = mx;
    }
    bool nb = (mxv[0] > m_[0] + 8.f) || (mxv[1] > m_[1] + 8.f);
    if (__any(nb)) {
#pragma unroll
      for (int f = 0; f < 2; ++f) {
        float mn = fmaxf(m_[f], mxv[f]);
        float so = exp2f(m_[f] - mn);
        m_[f] = mn;
        l_[f] *= so;
        float sob[4];
#pragma unroll
        for (int r = 0; r < 4; ++r) sob[r] = __shfl(so, kgrp * 4 + r, 16);
#pragma unroll
        for (int nd = 0; nd < 8; ++nd)
#pragma unroll
          for (int r = 0; r < 4; ++r) acc[f][nd][r] *= sob[r];
      }
    }

    float lp[2] = {0.f, 0.f};
#pragma unroll
    for (int half = 0; half < 2; ++half) {
      s16x8 pa[2][2];
#pragma unroll
      for (int f = 0; f < 2; ++f) {
#pragma unroll
        for (int cf = 0; cf < 4; ++cf) {
          int cfs = half * 4 + cf;
          bf16 pk[4];
#pragma unroll
          for (int r = 0; r < 4; ++r) {
            float p = exp2f(sc[f][cfs][r] * SCALE2 - m_[f]);
            lp[f] += p;
            pk[r] = __float2bfloat16(p);
          }
          __builtin_memcpy((void*)&P_lds[w][lrow][cf * 16 + kgrp * 4], pk, 8);
        }
#pragma unroll
        for (int kc = 0; kc < 2; ++kc)
          pa[f][kc] = *(const s16x8*)&P_lds[w][lrow][kc * 32 + kgrp * 8];
      }
#pragma unroll
      for (int nd = 0; nd < 8; ++nd)
#pragma unroll
        for (int kc = 0; kc < 2; ++kc) {
          s16x8 vb = *(const s16x8*)&Vl[cur][nd * 16 + lrow]
                                       [((half * 8 + kc * 4 + kgrp) ^ lrow) * 8];
#pragma unroll
          for (int f = 0; f < 2; ++f) acc[f][nd] = MFMA(pa[f][kc], vb, acc[f][nd]);
        }
    }
#pragma unroll
    for (int f = 0; f < 2; ++f) l_[f] += lp[f];

    __syncthreads();  // drains K/V(t+1) DMA; protects cur bufs for next stage
  }
#undef STAGE_K
#undef STAGE_V

  float li[2][4];
#pragma unroll
  for (int f = 0; f < 2; ++f) {
    float lv = l_[f];
    lv += __shfl_xor(lv, 16, 64);
    lv += __shfl_xor(lv, 32, 64);
#pragma unroll
    for (int r = 0; r < 4; ++r) li[f][r] = 1.f / __shfl(lv, kgrp * 4 + r, 16);
  }
#pragma unroll
  for (int f = 0; f < 2; ++f)
#pragma unroll
    for (int nd = 0; nd < 8; ++nd)
#pragma unroll
      for (int r = 0; r < 4; ++r) {
        int row = qb * 256 + w * 32 + f * 16 + kgrp * 4 + r;
        O[((size_t)b * SS + row) * 2048 + h * HD + nd * 16 + lrow] =
            __float2bfloat16(acc[f][nd][r] * li[f][r]);
      }
}

// ---------------- launch ----------------

extern "C" void kernel_launch(void* const* d_in, const int* in_sizes, int n_in,
                              void* d_out, int out_size, void* d_ws, size_t ws_size,
                              hipStream_t stream) {
  const float* hs = (const float*)d_in[0];
  const float* Wqkv = (const float*)d_in[1];
  const float* Wo = (const float*)d_in[2];
  const float* ctx_k = (const float*)d_in[3];
  const float* ctx_v = (const float*)d_in[4];
  const int* pid = (const int*)d_in[5];
  float* out = (float*)d_out;
  char* ws = (char*)d_ws;

  bf16* Hb = (bf16*)(ws);                      // 16.78 MB (reused as attn_out)
  bf16* WqT = (bf16*)(ws + 16777216);          // 16.78 MB
  bf16* WoT = (bf16*)(ws + 33554432);          // 8.39 MB
  bf16* qkv = (bf16*)(ws + 41943040);          // 33.55 MB (only Q half written)
  bf16* Kfull = (bf16*)(ws + 92274688);        // 25.17 MB
  bf16* Vt = (bf16*)(ws + 117440512);          // 25.17 MB
  float* cosT = (float*)(ws + 142606336);      // 256 KB
  float* sinT = (float*)(ws + 142606336 + 262144);
  bf16* attn = Hb;  // alias: Hb dead after QKV GEMM

  prep1<<<P1_CV, 256, 0, stream>>>(hs, Wqkv, Wo, ctx_k, ctx_v, pid, Hb, WqT, WoT,
                                   Kfull, Vt, cosT, sinT);
  gemm_qkv<<<dim3(QKVN / 256, MROWS / 256), 512, 0, stream>>>(
      Hb, WqT, qkv, Kfull, Vt, cosT, sinT);
  flash_attn<<<256, 512, 0, stream>>>(qkv, cosT, sinT, Kfull, Vt, attn);
  gemm_bt<float><<<dim3(2048 / 128, MROWS / 256), 512, 0, stream>>>(
      attn, WoT, out, MROWS, 2048, HID);
}